// Round 3
// baseline (2340.759 us; speedup 1.0000x reference)
//
#include <hip/hip_runtime.h>
#include <hip/hip_bf16.h>

// ---- problem constants ----
#define BSZ 4
#define TT 64
#define NNODE 128
#define NFEAT 16
#define HIDD 64
#define NHEAD 4
#define RHID 256
#define LDIM 64
#define EPG 1024
#define NGRAPH (BSZ*TT)          // 256
#define NTOT (NGRAPH*NNODE)      // 32768
#define ESLOTS (EPG+NNODE)       // 1152 edges incl self-loops (base graph)

// ---- canonical fp32 weight buffer offsets (floats) ----
#define WOFF_G0W 0
#define WOFF_G0AS 4096
#define WOFF_G0AD 4352
#define WOFF_G0B 4608
#define WOFF_G1W 4864
#define WOFF_G1AS 70400
#define WOFF_G1AD 70656
#define WOFF_G1B 70912
#define WOFF_G2W 71168
#define WOFF_G2AS 87552
#define WOFF_G2AD 87616
#define WOFF_G2B 87680
#define WOFF_WIHF 87744
#define WOFF_WHHF 153280
#define WOFF_BIHF 415424
#define WOFF_BHHF 416448
#define WOFF_WIHB 417472
#define WOFF_WHHB 483008
#define WOFF_BIHB 745152
#define WOFF_BHHB 746176
#define WOFF_MUW 747200
#define WOFF_MUB 779968
#define WOFF_LVW 780032
#define WOFF_LVB 812800
#define WTOTAL   812864

// ---- workspace float offsets ----
#define FOFF_WBUF 4096
#define FOFF_ALS  1052672
#define FOFF_ALD  1183744
#define FOFF_MX   1314816
#define FOFF_IDEN 1445888
#define FOFF_WE   1576960
#define FOFF_XFP  2756608
#define FOFF_XBP  3018752
#define FOFF_HT   3280896
#define FOFF_XSEQ 3282944
#define FOFF_H    3291136
#define FOFF_P    7485440

__device__ __forceinline__ float b2f(unsigned short u){
  union { unsigned int i; float f; } v; v.i = ((unsigned int)u) << 16; return v.f;
}
__device__ __forceinline__ unsigned short f2b(float f){
  __hip_bfloat16 h = __float2bfloat16(f);
  union { __hip_bfloat16 h; unsigned short u; } v; v.h = h; return v.u;
}

// ---------------- dtype sniff: is gat0_W bf16 (1) or fp32 (0)? ----------------
__global__ void sniff_kernel(const unsigned short* __restrict__ w, int* __restrict__ flag){
  __shared__ int cnt;
  if (threadIdx.x == 0) cnt = 0;
  __syncthreads();
  int ok = 0;
  for (int i = threadIdx.x; i < 2048; i += 256){
    float a = fabsf(b2f(w[2 * i]));
    if (a > 1e-8f && a < 4.f) ok++;
  }
  atomicAdd(&cnt, ok);
  __syncthreads();
  if (threadIdx.x == 0) *flag = (cnt >= 1024) ? 1 : 0;
}

// ---------------- convert all float weights into one fp32 buffer ----------------
struct CvtArgs {
  const void* src[24];
  int off[25];
};
__global__ void cvtw_kernel(CvtArgs a, const int* __restrict__ flag, float* __restrict__ W){
  int t = blockIdx.x * blockDim.x + threadIdx.x;
  if (t >= WTOTAL) return;
  int k = 0;
  while (t >= a.off[k + 1]) ++k;
  int rel = t - a.off[k];
  float v;
  if (*flag) v = b2f(((const unsigned short*)a.src[k])[rel]);
  else       v = ((const float*)a.src[k])[rel];
  W[t] = v;
}

// ---------------- convert x -> bf16 node features ----------------
__global__ void cvtx_kernel(const void* __restrict__ x, const int* __restrict__ flag,
                            unsigned short* __restrict__ P){
  int i = blockIdx.x * blockDim.x + threadIdx.x;  // < NTOT*NFEAT
  if (*flag) P[i] = ((const unsigned short*)x)[i];
  else       P[i] = f2b(((const float*)x)[i]);
}

// ---------------- CSR build for the base graph ----------------
__global__ void csr_kernel(const int* __restrict__ ei, int* __restrict__ row,
                           int* __restrict__ colsrc, int* __restrict__ coldst){
  __shared__ int cnt[NNODE];
  __shared__ int off[NNODE];
  int tid = threadIdx.x;
  for (int i = tid; i < NNODE; i += blockDim.x) cnt[i] = 0;
  __syncthreads();
  for (int i = tid; i < ESLOTS; i += blockDim.x){
    int d = (i < EPG) ? ei[EPG + i] : (i - EPG);
    atomicAdd(&cnt[d], 1);
  }
  __syncthreads();
  if (tid == 0){
    int acc = 0;
    for (int i = 0; i < NNODE; ++i){ row[i] = acc; off[i] = acc; acc += cnt[i]; }
    row[NNODE] = acc;
  }
  __syncthreads();
  for (int i = tid; i < ESLOTS; i += blockDim.x){
    int s, d;
    if (i < EPG){ s = ei[i]; d = ei[EPG + i]; } else { s = i - EPG; d = i - EPG; }
    int pos = atomicAdd(&off[d], 1);
    colsrc[pos] = s; coldst[pos] = d;
  }
}

// ---------------- tiled matmul: C[M,Nc] = A[M,K] @ B ----------------
// A bf16 row-major. BT=0: B fp32 [K][Nc]; BT=1: B fp32 [Nc][K] used transposed.
// CBF16: write bf16 else fp32. Requires M%64==0, Nc%64==0, K%16==0.
template<int BT, int CBF16>
__global__ __launch_bounds__(256)
void mm_kernel(const unsigned short* __restrict__ A, const float* __restrict__ B,
               void* __restrict__ Cv, int M, int Nc, int K)
{
  __shared__ float As[16][68];
  __shared__ float Bs[16][68];
  const int tid = threadIdx.x;
  const int tx = tid & 15, ty = tid >> 4;
  const int m0 = blockIdx.x * 64, n0 = blockIdx.y * 64;
  float acc[4][4] = {};
  for (int kc = 0; kc < K; kc += 16){
    { // stage A: 64 rows x 16 k (bf16 -> fp32)
      int r = tid >> 2, kk0 = (tid & 3) << 2;
      uint2 u = *(const uint2*)(A + (size_t)(m0 + r) * K + kc + kk0);
      As[kk0+0][r] = b2f((unsigned short)(u.x & 0xffff));
      As[kk0+1][r] = b2f((unsigned short)(u.x >> 16));
      As[kk0+2][r] = b2f((unsigned short)(u.y & 0xffff));
      As[kk0+3][r] = b2f((unsigned short)(u.y >> 16));
    }
    if (BT == 0){
      int k = tid >> 4, c0 = (tid & 15) << 2;
      float4 bv = *(const float4*)(B + (size_t)(kc + k) * Nc + n0 + c0);
      Bs[k][c0+0] = bv.x; Bs[k][c0+1] = bv.y; Bs[k][c0+2] = bv.z; Bs[k][c0+3] = bv.w;
    } else {
      int n = tid >> 2, kk0 = (tid & 3) << 2;
      float4 bv = *(const float4*)(B + (size_t)(n0 + n) * K + kc + kk0);
      Bs[kk0+0][n] = bv.x; Bs[kk0+1][n] = bv.y; Bs[kk0+2][n] = bv.z; Bs[kk0+3][n] = bv.w;
    }
    __syncthreads();
    #pragma unroll
    for (int k = 0; k < 16; ++k){
      float4 av = *(const float4*)&As[k][ty << 2];
      float4 bv = *(const float4*)&Bs[k][tx << 2];
      float am[4] = {av.x, av.y, av.z, av.w};
      float bm[4] = {bv.x, bv.y, bv.z, bv.w};
      #pragma unroll
      for (int i = 0; i < 4; ++i)
        #pragma unroll
        for (int j = 0; j < 4; ++j) acc[i][j] += am[i] * bm[j];
    }
    __syncthreads();
  }
  if (CBF16){
    unsigned short* C = (unsigned short*)Cv;
    #pragma unroll
    for (int i = 0; i < 4; ++i){
      unsigned short* cp = C + (size_t)(m0 + (ty << 2) + i) * Nc + n0 + (tx << 2);
      #pragma unroll
      for (int j = 0; j < 4; ++j) cp[j] = f2b(acc[i][j]);
    }
  } else {
    float* C = (float*)Cv;
    #pragma unroll
    for (int i = 0; i < 4; ++i){
      float* cp = C + (size_t)(m0 + (ty << 2) + i) * Nc + n0 + (tx << 2);
      #pragma unroll
      for (int j = 0; j < 4; ++j) cp[j] = acc[i][j];
    }
  }
}

// ---------------- attention logits per (node, head): block = node ----------------
__global__ void al_kernel(const unsigned short* __restrict__ H, const float* __restrict__ asrc,
                          const float* __restrict__ adst,
                          float* __restrict__ ALS, float* __restrict__ ALD, int HD, int Hh)
{
  int n = blockIdx.x;
  int tid = threadIdx.x;
  float hv = b2f(H[(size_t)n * HD + tid]);
  float vs = hv * asrc[tid];
  float vd = hv * adst[tid];
  #pragma unroll
  for (int m = 32; m >= 1; m >>= 1){ vs += __shfl_xor(vs, m); vd += __shfl_xor(vd, m); }
  if ((tid & 63) == 0){
    int h = tid >> 6;
    ALS[(size_t)n * Hh + h] = vs;
    ALD[(size_t)n * Hh + h] = vd;
  }
}

// ---------------- online softmax max + inv-denominator per (dst,head) ----------------
__global__ void mden_kernel(const float* __restrict__ ALS, const float* __restrict__ ALD,
                            const int* __restrict__ row, const int* __restrict__ colsrc,
                            float* __restrict__ MX, float* __restrict__ IDEN, int Hh)
{
  int id = blockIdx.x * blockDim.x + threadIdx.x;
  if (id >= NTOT * Hh) return;
  int h = id % Hh, n = id / Hh;
  int g = n >> 7, dn = n & 127;
  float aldv = ALD[(size_t)n * Hh + h];
  int rs = row[dn], re = row[dn + 1];
  float mx = -1e30f, den = 0.f;
  for (int j = rs; j < re; ++j){
    int s = colsrc[j];
    float v = ALS[(size_t)(g * NNODE + s) * Hh + h] + aldv;
    v = v > 0.f ? v : 0.2f * v;
    if (v > mx){ den = den * __expf(mx - v) + 1.f; mx = v; }
    else den += __expf(v - mx);
  }
  MX[id] = mx;
  IDEN[id] = 1.f / (den + 1e-16f);
}

// ---------------- per-edge softmax weight ----------------
__global__ void edgew_kernel(const float* __restrict__ ALS, const float* __restrict__ ALD,
                             const float* __restrict__ MX, const float* __restrict__ IDEN,
                             const int* __restrict__ colsrc, const int* __restrict__ coldst,
                             float* __restrict__ WE, int Hh)
{
  int id = blockIdx.x * blockDim.x + threadIdx.x;
  if (id >= NGRAPH * ESLOTS * Hh) return;
  int h = id % Hh;
  int rest = id / Hh;
  int slot = rest % ESLOTS;
  int g = rest / ESLOTS;
  int s = colsrc[slot], d = coldst[slot];
  int gd = (g * NNODE + d) * Hh + h;
  float e = ALS[(size_t)(g * NNODE + s) * Hh + h] + ALD[gd];
  e = e > 0.f ? e : 0.2f * e;
  WE[id] = __expf(e - MX[gd]) * IDEN[gd];
}

// ---------------- aggregate + bias + relu: block = dst node ----------------
__global__ void agg_kernel(const unsigned short* __restrict__ H, const float* __restrict__ WE,
                           const int* __restrict__ row, const int* __restrict__ colsrc,
                           const float* __restrict__ bias,
                           unsigned short* __restrict__ O, int HD, int Hh)
{
  int n = blockIdx.x, tid = threadIdx.x;
  int g = n >> 7, dn = n & 127;
  int h = tid >> 6;
  int rs = row[dn], re = row[dn + 1];
  const unsigned short* Hg = H + (size_t)g * NNODE * HD;
  const float* WEg = WE + (size_t)g * ESLOTS * Hh;
  float acc = 0.f;
  for (int j = rs; j < re; ++j){
    int s = colsrc[j];
    float w = WEg[j * Hh + h];
    acc += w * b2f(Hg[(size_t)s * HD + tid]);
  }
  float o = acc + bias[tid];
  O[(size_t)n * HD + tid] = f2b(o > 0.f ? o : 0.f);
}

// ---------------- graph sum-pool, write seq layout [t][b][HIDD] (bf16) ----------------
__global__ void pool_kernel(const unsigned short* __restrict__ X3, unsigned short* __restrict__ XSEQ){
  int id = blockIdx.x * blockDim.x + threadIdx.x; // NGRAPH*HIDD
  if (id >= NGRAPH * HIDD) return;
  int g = id >> 6, f = id & 63;
  const unsigned short* p = X3 + (size_t)g * NNODE * HIDD + f;
  float s = 0.f;
  for (int dn = 0; dn < NNODE; ++dn) s += b2f(p[dn * HIDD]);
  int b = g >> 6, t = g & 63;           // g = b*TT + t
  XSEQ[(size_t)(t * BSZ + b) * HIDD + f] = f2b(s);
}

// ---------------- bidirectional LSTM recurrence: block = (dir, batch) ----------------
__global__ __launch_bounds__(1024)
void lstm_kernel(const float* __restrict__ XF, const float* __restrict__ XB,
                 const float* __restrict__ Whh_f, const float* __restrict__ Whh_b,
                 const float* __restrict__ bih_f, const float* __restrict__ bhh_f,
                 const float* __restrict__ bih_b, const float* __restrict__ bhh_b,
                 float* __restrict__ HT)
{
  __shared__ float h_lds[RHID];
  __shared__ float g_lds[4 * RHID];
  int u = threadIdx.x;
  int b = blockIdx.x & 3, dir = blockIdx.x >> 2;
  const float* Xp = dir ? XB : XF;
  const float* Whh = dir ? Whh_b : Whh_f;
  float bias = (dir ? bih_b : bih_f)[u] + (dir ? bhh_b : bhh_f)[u];
  const float* wrow = Whh + (size_t)u * RHID;
  float c = 0.f;
  if (u < RHID) h_lds[u] = 0.f;
  __syncthreads();
  for (int t = 0; t < TT; ++t){
    int trow = dir ? ((TT - 1 - t) * BSZ + b) : (t * BSZ + b);
    float acc = bias + Xp[(size_t)trow * (4 * RHID) + u];
    #pragma unroll 4
    for (int k = 0; k < RHID; k += 8){
      float4 w0 = *(const float4*)(wrow + k);
      float4 w1 = *(const float4*)(wrow + k + 4);
      float4 h0 = *(const float4*)&h_lds[k];
      float4 h1 = *(const float4*)&h_lds[k + 4];
      acc += w0.x * h0.x + w0.y * h0.y + w0.z * h0.z + w0.w * h0.w;
      acc += w1.x * h1.x + w1.y * h1.y + w1.z * h1.z + w1.w * h1.w;
    }
    g_lds[u] = acc;
    __syncthreads();
    if (u < RHID){
      float gi = g_lds[u], gf = g_lds[RHID + u], gg = g_lds[2 * RHID + u], go = g_lds[3 * RHID + u];
      float si = 1.f / (1.f + __expf(-gi));
      float sf = 1.f / (1.f + __expf(-gf));
      float so = 1.f / (1.f + __expf(-go));
      float tg = 1.f - 2.f / (1.f + __expf(2.f * gg));
      c = sf * c + si * tg;
      float ch = 1.f - 2.f / (1.f + __expf(2.f * c));
      h_lds[u] = so * ch;
    }
    __syncthreads();
  }
  if (u < RHID) HT[(size_t)blockIdx.x * RHID + u] = h_lds[u];
}

// ---------------- heads + Poincare projection, fp32 out ----------------
__global__ void head_kernel(const float* __restrict__ HT,
                            const float* __restrict__ muW, const float* __restrict__ mub,
                            const float* __restrict__ lvW, const float* __restrict__ lvb,
                            float* __restrict__ out)
{
  int tid = threadIdx.x;            // 256
  int b = tid >> 6, j = tid & 63;   // wave = one batch row
  const float* hf = HT + (size_t)b * RHID;
  const float* hb = HT + (size_t)(4 + b) * RHID;
  float mu = mub[j], lv = lvb[j];
  const float* mw = muW + (size_t)j * (2 * RHID);
  const float* lw = lvW + (size_t)j * (2 * RHID);
  for (int k = 0; k < RHID; ++k){
    float f0 = hf[k], f1 = hb[k];
    mu += f0 * mw[k] + f1 * mw[RHID + k];
    lv += f0 * lw[k] + f1 * lw[RHID + k];
  }
  float sq = mu * mu;
  #pragma unroll
  for (int m = 32; m >= 1; m >>= 1) sq += __shfl_xor(sq, m);
  float nrm = sqrtf(sq);
  const float maxnorm = 1.0f - 4e-3f;
  if (nrm > maxnorm) mu = mu / nrm * maxnorm;
  out[b * 64 + j] = mu;
  out[256 + b * 64 + j] = lv;
}

extern "C" void kernel_launch(void* const* d_in, const int* in_sizes, int n_in,
                              void* d_out, int out_size, void* d_ws, size_t ws_size,
                              hipStream_t stream)
{
  const int* ei = (const int*)d_in[1];

  int*   ws_i    = (int*)d_ws;
  int*   dflag   = ws_i;                 // [0]
  int*   csr_row = ws_i + 256;           // 129
  int*   csr_src = ws_i + 512;           // 1152
  int*   csr_dst = ws_i + 2048;          // 1152
  float* FW   = (float*)d_ws;
  float* Wbuf = FW + FOFF_WBUF;
  float* ALS  = FW + FOFF_ALS;
  float* ALD  = FW + FOFF_ALD;
  float* MX   = FW + FOFF_MX;
  float* IDEN = FW + FOFF_IDEN;
  float* WE   = FW + FOFF_WE;
  float* XFp  = FW + FOFF_XFP;
  float* XBp  = FW + FOFF_XBP;
  float* HT   = FW + FOFF_HT;
  unsigned short* XSEQ = (unsigned short*)(FW + FOFF_XSEQ);
  unsigned short* Hb   = (unsigned short*)(FW + FOFF_H);
  unsigned short* Pb   = (unsigned short*)(FW + FOFF_P);

  // ---- dtype sniff + canonicalize inputs ----
  sniff_kernel<<<1, 256, 0, stream>>>((const unsigned short*)d_in[2], dflag);

  CvtArgs ca;
  static const int wsz[24] = {4096,256,256,256, 65536,256,256,256, 16384,64,64,64,
                              65536,262144,1024,1024, 65536,262144,1024,1024,
                              32768,64,32768,64};
  {
    int acc = 0;
    for (int k = 0; k < 24; ++k){ ca.src[k] = d_in[2 + k]; ca.off[k] = acc; acc += wsz[k]; }
    ca.off[24] = acc;  // WTOTAL
  }
  cvtw_kernel<<<(WTOTAL + 255) / 256, 256, 0, stream>>>(ca, dflag, Wbuf);
  cvtx_kernel<<<(NTOT * NFEAT) / 256, 256, 0, stream>>>(d_in[0], dflag, Pb);
  csr_kernel<<<1, 256, 0, stream>>>(ei, csr_row, csr_src, csr_dst);

  // ---- GAT layer 0: P[32768,16] @ g0W[16,256] -> H ----
  mm_kernel<0,1><<<dim3(512, 4), 256, 0, stream>>>(Pb, Wbuf + WOFF_G0W, Hb, NTOT, 256, 16);
  al_kernel<<<NTOT, 256, 0, stream>>>(Hb, Wbuf + WOFF_G0AS, Wbuf + WOFF_G0AD, ALS, ALD, 256, 4);
  mden_kernel<<<(NTOT * 4) / 256, 256, 0, stream>>>(ALS, ALD, csr_row, csr_src, MX, IDEN, 4);
  edgew_kernel<<<(NGRAPH * ESLOTS * 4) / 256, 256, 0, stream>>>(ALS, ALD, MX, IDEN, csr_src, csr_dst, WE, 4);
  agg_kernel<<<NTOT, 256, 0, stream>>>(Hb, WE, csr_row, csr_src, Wbuf + WOFF_G0B, Pb, 256, 4);

  // ---- GAT layer 1: P[32768,256] @ g1W[256,256] -> H ----
  mm_kernel<0,1><<<dim3(512, 4), 256, 0, stream>>>(Pb, Wbuf + WOFF_G1W, Hb, NTOT, 256, 256);
  al_kernel<<<NTOT, 256, 0, stream>>>(Hb, Wbuf + WOFF_G1AS, Wbuf + WOFF_G1AD, ALS, ALD, 256, 4);
  mden_kernel<<<(NTOT * 4) / 256, 256, 0, stream>>>(ALS, ALD, csr_row, csr_src, MX, IDEN, 4);
  edgew_kernel<<<(NGRAPH * ESLOTS * 4) / 256, 256, 0, stream>>>(ALS, ALD, MX, IDEN, csr_src, csr_dst, WE, 4);
  agg_kernel<<<NTOT, 256, 0, stream>>>(Hb, WE, csr_row, csr_src, Wbuf + WOFF_G1B, Pb, 256, 4);

  // ---- GAT layer 2: P[32768,256] @ g2W[256,64] -> H, 1 head ----
  mm_kernel<0,1><<<dim3(512, 1), 256, 0, stream>>>(Pb, Wbuf + WOFF_G2W, Hb, NTOT, 64, 256);
  al_kernel<<<NTOT, 64, 0, stream>>>(Hb, Wbuf + WOFF_G2AS, Wbuf + WOFF_G2AD, ALS, ALD, 64, 1);
  mden_kernel<<<NTOT / 256, 256, 0, stream>>>(ALS, ALD, csr_row, csr_src, MX, IDEN, 1);
  edgew_kernel<<<(NGRAPH * ESLOTS) / 256, 256, 0, stream>>>(ALS, ALD, MX, IDEN, csr_src, csr_dst, WE, 1);
  agg_kernel<<<NTOT, 64, 0, stream>>>(Hb, WE, csr_row, csr_src, Wbuf + WOFF_G2B, Pb, 64, 1);

  // ---- pool + LSTM input precompute ----
  pool_kernel<<<(NGRAPH * HIDD) / 256, 256, 0, stream>>>(Pb, XSEQ);
  mm_kernel<1,0><<<dim3(4, 16), 256, 0, stream>>>(XSEQ, Wbuf + WOFF_WIHF, XFp, 256, 1024, 64);
  mm_kernel<1,0><<<dim3(4, 16), 256, 0, stream>>>(XSEQ, Wbuf + WOFF_WIHB, XBp, 256, 1024, 64);

  // ---- recurrence: 8 blocks = 2 dirs x 4 batches ----
  lstm_kernel<<<8, 1024, 0, stream>>>(XFp, XBp, Wbuf + WOFF_WHHF, Wbuf + WOFF_WHHB,
                                      Wbuf + WOFF_BIHF, Wbuf + WOFF_BHHF,
                                      Wbuf + WOFF_BIHB, Wbuf + WOFF_BHHB, HT);

  // ---- heads + projection ----
  head_kernel<<<1, 256, 0, stream>>>(HT, Wbuf + WOFF_MUW, Wbuf + WOFF_MUB,
                                     Wbuf + WOFF_LVW, Wbuf + WOFF_LVB, (float*)d_out);
}

// Round 4
// 925.561 us; speedup vs baseline: 2.5290x; 2.5290x over previous
//
#include <hip/hip_runtime.h>
#include <hip/hip_bf16.h>

// ---- problem constants ----
#define BSZ 4
#define TT 64
#define NNODE 128
#define NFEAT 16
#define HIDD 64
#define NHEAD 4
#define RHID 256
#define LDIM 64
#define EPG 1024
#define NGRAPH (BSZ*TT)          // 256
#define NTOT (NGRAPH*NNODE)      // 32768
#define ESLOTS (EPG+NNODE)       // 1152 edges incl self-loops (base graph)

// ---- canonical fp32 weight buffer offsets (floats) ----
#define WOFF_G0W 0
#define WOFF_G0AS 4096
#define WOFF_G0AD 4352
#define WOFF_G0B 4608
#define WOFF_G1W 4864
#define WOFF_G1AS 70400
#define WOFF_G1AD 70656
#define WOFF_G1B 70912
#define WOFF_G2W 71168
#define WOFF_G2AS 87552
#define WOFF_G2AD 87616
#define WOFF_G2B 87680
#define WOFF_WIHF 87744
#define WOFF_WHHF 153280
#define WOFF_BIHF 415424
#define WOFF_BHHF 416448
#define WOFF_WIHB 417472
#define WOFF_WHHB 483008
#define WOFF_BIHB 745152
#define WOFF_BHHB 746176
#define WOFF_MUW 747200
#define WOFF_MUB 779968
#define WOFF_LVW 780032
#define WOFF_LVB 812800
#define WTOTAL   812864

// ---- workspace float offsets ----
#define FOFF_WBUF 4096
#define FOFF_ALS  1052672
#define FOFF_ALD  1183744
#define FOFF_MX   1314816
#define FOFF_IDEN 1445888
#define FOFF_WE   1576960
#define FOFF_XFP  2756608
#define FOFF_XBP  3018752
#define FOFF_HT   3280896
#define FOFF_XSEQ 3282944
#define FOFF_H    3291136
#define FOFF_P    7485440

__device__ __forceinline__ float b2f(unsigned short u){
  union { unsigned int i; float f; } v; v.i = ((unsigned int)u) << 16; return v.f;
}
__device__ __forceinline__ unsigned short f2b(float f){
  __hip_bfloat16 h = __float2bfloat16(f);
  union { __hip_bfloat16 h; unsigned short u; } v; v.h = h; return v.u;
}

// fused half2 dot: acc += w.x*h.x + w.y*h.y   (v_dot2_f32_f16 when available)
__device__ __forceinline__ float dot2h(unsigned int w, unsigned int h, float acc){
#if __has_builtin(__builtin_amdgcn_fdot2)
  typedef _Float16 h2v __attribute__((ext_vector_type(2)));
  union { unsigned int u; h2v v; } a, b; a.u = w; b.u = h;
  return __builtin_amdgcn_fdot2(a.v, b.v, acc, false);
#else
  union { unsigned int u; _Float16 h[2]; } a, b; a.u = w; b.u = h;
  return acc + (float)a.h[0] * (float)b.h[0] + (float)a.h[1] * (float)b.h[1];
#endif
}

// ---------------- dtype sniff: is gat0_W bf16 (1) or fp32 (0)? ----------------
__global__ void sniff_kernel(const unsigned short* __restrict__ w, int* __restrict__ flag){
  __shared__ int cnt;
  if (threadIdx.x == 0) cnt = 0;
  __syncthreads();
  int ok = 0;
  for (int i = threadIdx.x; i < 2048; i += 256){
    float a = fabsf(b2f(w[2 * i]));
    if (a > 1e-8f && a < 4.f) ok++;
  }
  atomicAdd(&cnt, ok);
  __syncthreads();
  if (threadIdx.x == 0) *flag = (cnt >= 1024) ? 1 : 0;
}

// ---------------- convert all float weights into one fp32 buffer ----------------
struct CvtArgs {
  const void* src[24];
  int off[25];
};
__global__ void cvtw_kernel(CvtArgs a, const int* __restrict__ flag, float* __restrict__ W){
  int t = blockIdx.x * blockDim.x + threadIdx.x;
  if (t >= WTOTAL) return;
  int k = 0;
  while (t >= a.off[k + 1]) ++k;
  int rel = t - a.off[k];
  float v;
  if (*flag) v = b2f(((const unsigned short*)a.src[k])[rel]);
  else       v = ((const float*)a.src[k])[rel];
  W[t] = v;
}

// ---------------- convert x -> bf16 node features ----------------
__global__ void cvtx_kernel(const void* __restrict__ x, const int* __restrict__ flag,
                            unsigned short* __restrict__ P){
  int i = blockIdx.x * blockDim.x + threadIdx.x;  // < NTOT*NFEAT
  if (*flag) P[i] = ((const unsigned short*)x)[i];
  else       P[i] = f2b(((const float*)x)[i]);
}

// ---------------- CSR build for the base graph ----------------
__global__ void csr_kernel(const int* __restrict__ ei, int* __restrict__ row,
                           int* __restrict__ colsrc, int* __restrict__ coldst){
  __shared__ int cnt[NNODE];
  __shared__ int off[NNODE];
  int tid = threadIdx.x;
  for (int i = tid; i < NNODE; i += blockDim.x) cnt[i] = 0;
  __syncthreads();
  for (int i = tid; i < ESLOTS; i += blockDim.x){
    int d = (i < EPG) ? ei[EPG + i] : (i - EPG);
    atomicAdd(&cnt[d], 1);
  }
  __syncthreads();
  if (tid == 0){
    int acc = 0;
    for (int i = 0; i < NNODE; ++i){ row[i] = acc; off[i] = acc; acc += cnt[i]; }
    row[NNODE] = acc;
  }
  __syncthreads();
  for (int i = tid; i < ESLOTS; i += blockDim.x){
    int s, d;
    if (i < EPG){ s = ei[i]; d = ei[EPG + i]; } else { s = i - EPG; d = i - EPG; }
    int pos = atomicAdd(&off[d], 1);
    colsrc[pos] = s; coldst[pos] = d;
  }
}

// ---------------- tiled matmul: C[M,Nc] = A[M,K] @ B ----------------
template<int BT, int CBF16>
__global__ __launch_bounds__(256)
void mm_kernel(const unsigned short* __restrict__ A, const float* __restrict__ B,
               void* __restrict__ Cv, int M, int Nc, int K)
{
  __shared__ float As[16][68];
  __shared__ float Bs[16][68];
  const int tid = threadIdx.x;
  const int tx = tid & 15, ty = tid >> 4;
  const int m0 = blockIdx.x * 64, n0 = blockIdx.y * 64;
  float acc[4][4] = {};
  for (int kc = 0; kc < K; kc += 16){
    {
      int r = tid >> 2, kk0 = (tid & 3) << 2;
      uint2 u = *(const uint2*)(A + (size_t)(m0 + r) * K + kc + kk0);
      As[kk0+0][r] = b2f((unsigned short)(u.x & 0xffff));
      As[kk0+1][r] = b2f((unsigned short)(u.x >> 16));
      As[kk0+2][r] = b2f((unsigned short)(u.y & 0xffff));
      As[kk0+3][r] = b2f((unsigned short)(u.y >> 16));
    }
    if (BT == 0){
      int k = tid >> 4, c0 = (tid & 15) << 2;
      float4 bv = *(const float4*)(B + (size_t)(kc + k) * Nc + n0 + c0);
      Bs[k][c0+0] = bv.x; Bs[k][c0+1] = bv.y; Bs[k][c0+2] = bv.z; Bs[k][c0+3] = bv.w;
    } else {
      int n = tid >> 2, kk0 = (tid & 3) << 2;
      float4 bv = *(const float4*)(B + (size_t)(n0 + n) * K + kc + kk0);
      Bs[kk0+0][n] = bv.x; Bs[kk0+1][n] = bv.y; Bs[kk0+2][n] = bv.z; Bs[kk0+3][n] = bv.w;
    }
    __syncthreads();
    #pragma unroll
    for (int k = 0; k < 16; ++k){
      float4 av = *(const float4*)&As[k][ty << 2];
      float4 bv = *(const float4*)&Bs[k][tx << 2];
      float am[4] = {av.x, av.y, av.z, av.w};
      float bm[4] = {bv.x, bv.y, bv.z, bv.w};
      #pragma unroll
      for (int i = 0; i < 4; ++i)
        #pragma unroll
        for (int j = 0; j < 4; ++j) acc[i][j] += am[i] * bm[j];
    }
    __syncthreads();
  }
  if (CBF16){
    unsigned short* C = (unsigned short*)Cv;
    #pragma unroll
    for (int i = 0; i < 4; ++i){
      unsigned short* cp = C + (size_t)(m0 + (ty << 2) + i) * Nc + n0 + (tx << 2);
      #pragma unroll
      for (int j = 0; j < 4; ++j) cp[j] = f2b(acc[i][j]);
    }
  } else {
    float* C = (float*)Cv;
    #pragma unroll
    for (int i = 0; i < 4; ++i){
      float* cp = C + (size_t)(m0 + (ty << 2) + i) * Nc + n0 + (tx << 2);
      #pragma unroll
      for (int j = 0; j < 4; ++j) cp[j] = acc[i][j];
    }
  }
}

// ---------------- attention logits per (node, head): block = node ----------------
__global__ void al_kernel(const unsigned short* __restrict__ H, const float* __restrict__ asrc,
                          const float* __restrict__ adst,
                          float* __restrict__ ALS, float* __restrict__ ALD, int HD, int Hh)
{
  int n = blockIdx.x;
  int tid = threadIdx.x;
  float hv = b2f(H[(size_t)n * HD + tid]);
  float vs = hv * asrc[tid];
  float vd = hv * adst[tid];
  #pragma unroll
  for (int m = 32; m >= 1; m >>= 1){ vs += __shfl_xor(vs, m); vd += __shfl_xor(vd, m); }
  if ((tid & 63) == 0){
    int h = tid >> 6;
    ALS[(size_t)n * Hh + h] = vs;
    ALD[(size_t)n * Hh + h] = vd;
  }
}

// ---------------- online softmax max + inv-denominator per (dst,head) ----------------
__global__ void mden_kernel(const float* __restrict__ ALS, const float* __restrict__ ALD,
                            const int* __restrict__ row, const int* __restrict__ colsrc,
                            float* __restrict__ MX, float* __restrict__ IDEN, int Hh)
{
  int id = blockIdx.x * blockDim.x + threadIdx.x;
  if (id >= NTOT * Hh) return;
  int h = id % Hh, n = id / Hh;
  int g = n >> 7, dn = n & 127;
  float aldv = ALD[(size_t)n * Hh + h];
  int rs = row[dn], re = row[dn + 1];
  float mx = -1e30f, den = 0.f;
  for (int j = rs; j < re; ++j){
    int s = colsrc[j];
    float v = ALS[(size_t)(g * NNODE + s) * Hh + h] + aldv;
    v = v > 0.f ? v : 0.2f * v;
    if (v > mx){ den = den * __expf(mx - v) + 1.f; mx = v; }
    else den += __expf(v - mx);
  }
  MX[id] = mx;
  IDEN[id] = 1.f / (den + 1e-16f);
}

// ---------------- per-edge softmax weight ----------------
__global__ void edgew_kernel(const float* __restrict__ ALS, const float* __restrict__ ALD,
                             const float* __restrict__ MX, const float* __restrict__ IDEN,
                             const int* __restrict__ colsrc, const int* __restrict__ coldst,
                             float* __restrict__ WE, int Hh)
{
  int id = blockIdx.x * blockDim.x + threadIdx.x;
  if (id >= NGRAPH * ESLOTS * Hh) return;
  int h = id % Hh;
  int rest = id / Hh;
  int slot = rest % ESLOTS;
  int g = rest / ESLOTS;
  int s = colsrc[slot], d = coldst[slot];
  int gd = (g * NNODE + d) * Hh + h;
  float e = ALS[(size_t)(g * NNODE + s) * Hh + h] + ALD[gd];
  e = e > 0.f ? e : 0.2f * e;
  WE[id] = __expf(e - MX[gd]) * IDEN[gd];
}

// ---------------- aggregate + bias + relu: block = dst node ----------------
__global__ void agg_kernel(const unsigned short* __restrict__ H, const float* __restrict__ WE,
                           const int* __restrict__ row, const int* __restrict__ colsrc,
                           const float* __restrict__ bias,
                           unsigned short* __restrict__ O, int HD, int Hh)
{
  int n = blockIdx.x, tid = threadIdx.x;
  int g = n >> 7, dn = n & 127;
  int h = tid >> 6;
  int rs = row[dn], re = row[dn + 1];
  const unsigned short* Hg = H + (size_t)g * NNODE * HD;
  const float* WEg = WE + (size_t)g * ESLOTS * Hh;
  float acc = 0.f;
  for (int j = rs; j < re; ++j){
    int s = colsrc[j];
    float w = WEg[j * Hh + h];
    acc += w * b2f(Hg[(size_t)s * HD + tid]);
  }
  float o = acc + bias[tid];
  O[(size_t)n * HD + tid] = f2b(o > 0.f ? o : 0.f);
}

// ---------------- graph sum-pool, write seq layout [t][b][HIDD] (bf16) ----------------
__global__ void pool_kernel(const unsigned short* __restrict__ X3, unsigned short* __restrict__ XSEQ){
  int id = blockIdx.x * blockDim.x + threadIdx.x; // NGRAPH*HIDD
  if (id >= NGRAPH * HIDD) return;
  int g = id >> 6, f = id & 63;
  const unsigned short* p = X3 + (size_t)g * NNODE * HIDD + f;
  float s = 0.f;
  for (int dn = 0; dn < NNODE; ++dn) s += b2f(p[dn * HIDD]);
  int b = g >> 6, t = g & 63;           // g = b*TT + t
  XSEQ[(size_t)(t * BSZ + b) * HIDD + f] = f2b(s);
}

// ---------------- pack Whh (both dirs) into f16-pair, load-interleaved layout ----------------
// WT[d][kk4][u][c] (uint) packs K-pair (2*(kk4*4+c), +1) of gate-row u, dir d.
__global__ void packwhh_kernel(const float* __restrict__ Wbuf, unsigned int* __restrict__ WT){
  int id = blockIdx.x * blockDim.x + threadIdx.x;   // < 262144
  int d = id >> 17;
  int r = id & 131071;
  int c = r & 3;
  int u = (r >> 2) & 1023;
  int kk4 = r >> 12;                                // 0..31
  int kk = kk4 * 4 + c;
  const float* W = Wbuf + (d ? WOFF_WHHB : WOFF_WHHF);
  _Float16 a = (_Float16)W[u * RHID + 2 * kk];
  _Float16 b = (_Float16)W[u * RHID + 2 * kk + 1];
  union { _Float16 h; unsigned short s; } ua, ub; ua.h = a; ub.h = b;
  WT[id] = (unsigned int)ua.s | ((unsigned int)ub.s << 16);
}

// ---------------- bidirectional LSTM: block = direction, 4 batches per block ----------------
__global__ __launch_bounds__(1024)
void lstm2_kernel(const float* __restrict__ XF, const float* __restrict__ XB,
                  const unsigned int* __restrict__ WT,
                  const float* __restrict__ bih_f, const float* __restrict__ bhh_f,
                  const float* __restrict__ bih_b, const float* __restrict__ bhh_b,
                  float* __restrict__ HT)
{
  __shared__ unsigned short h2s[4 * RHID];   // per-batch h, f16 packed pairs (uint view [4][128])
  __shared__ float glds[4][1024];            // gates per batch
  const int u = threadIdx.x;
  const int dir = blockIdx.x;
  const float* Xp = dir ? XB : XF;
  const unsigned int* Wd = WT + (dir << 17);           // [32][1024][4] uints
  const float bias = (dir ? bih_b : bih_f)[u] + (dir ? bhh_b : bhh_f)[u];
  const int ub = u >> 8, uj = u & 255;                 // updater: (batch, unit)
  const unsigned int* h2u = (const unsigned int*)h2s;  // [4][128]
  float c = 0.f;
  h2s[u] = 0;                                          // 4*256 = 1024 halves
  __syncthreads();
  for (int t = 0; t < TT; ++t){
    const int tb = dir ? (TT - 1 - t) : t;
    const float* xr = Xp + (size_t)(tb * 4) * 1024 + u;
    float a0 = bias + xr[0];
    float a1 = bias + xr[1024];
    float a2 = bias + xr[2048];
    float a3 = bias + xr[3072];
    #pragma unroll 4
    for (int kk4 = 0; kk4 < 32; ++kk4){
      uint4 w4 = *(const uint4*)(Wd + (((size_t)kk4 << 10) + u) * 4);
      uint4 hb0 = *(const uint4*)(h2u + 0 * 128 + (kk4 << 2));
      uint4 hb1 = *(const uint4*)(h2u + 1 * 128 + (kk4 << 2));
      uint4 hb2 = *(const uint4*)(h2u + 2 * 128 + (kk4 << 2));
      uint4 hb3 = *(const uint4*)(h2u + 3 * 128 + (kk4 << 2));
      a0 = dot2h(w4.x, hb0.x, a0); a0 = dot2h(w4.y, hb0.y, a0);
      a0 = dot2h(w4.z, hb0.z, a0); a0 = dot2h(w4.w, hb0.w, a0);
      a1 = dot2h(w4.x, hb1.x, a1); a1 = dot2h(w4.y, hb1.y, a1);
      a1 = dot2h(w4.z, hb1.z, a1); a1 = dot2h(w4.w, hb1.w, a1);
      a2 = dot2h(w4.x, hb2.x, a2); a2 = dot2h(w4.y, hb2.y, a2);
      a2 = dot2h(w4.z, hb2.z, a2); a2 = dot2h(w4.w, hb2.w, a2);
      a3 = dot2h(w4.x, hb3.x, a3); a3 = dot2h(w4.y, hb3.y, a3);
      a3 = dot2h(w4.z, hb3.z, a3); a3 = dot2h(w4.w, hb3.w, a3);
    }
    glds[0][u] = a0; glds[1][u] = a1; glds[2][u] = a2; glds[3][u] = a3;
    __syncthreads();
    {
      float gi = glds[ub][uj];
      float gf = glds[ub][256 + uj];
      float gg = glds[ub][512 + uj];
      float go = glds[ub][768 + uj];
      float si = 1.f / (1.f + __expf(-gi));
      float sf = 1.f / (1.f + __expf(-gf));
      float so = 1.f / (1.f + __expf(-go));
      float tg = 1.f - 2.f / (1.f + __expf(2.f * gg));
      c = sf * c + si * tg;
      float ch = 1.f - 2.f / (1.f + __expf(2.f * c));
      float hval = so * ch;
      union { _Float16 h; unsigned short s; } uh; uh.h = (_Float16)hval;
      h2s[ub * RHID + uj] = uh.s;
      if (t == TT - 1) HT[(size_t)(dir * 4 + ub) * RHID + uj] = hval;
    }
    __syncthreads();
  }
}

// ---------------- heads + Poincare projection, fp32 out ----------------
__global__ void head_kernel(const float* __restrict__ HT,
                            const float* __restrict__ muW, const float* __restrict__ mub,
                            const float* __restrict__ lvW, const float* __restrict__ lvb,
                            float* __restrict__ out)
{
  int tid = threadIdx.x;            // 256
  int b = tid >> 6, j = tid & 63;   // wave = one batch row
  const float* hf = HT + (size_t)b * RHID;
  const float* hb = HT + (size_t)(4 + b) * RHID;
  float mu = mub[j], lv = lvb[j];
  const float* mw = muW + (size_t)j * (2 * RHID);
  const float* lw = lvW + (size_t)j * (2 * RHID);
  for (int k = 0; k < RHID; ++k){
    float f0 = hf[k], f1 = hb[k];
    mu += f0 * mw[k] + f1 * mw[RHID + k];
    lv += f0 * lw[k] + f1 * lw[RHID + k];
  }
  float sq = mu * mu;
  #pragma unroll
  for (int m = 32; m >= 1; m >>= 1) sq += __shfl_xor(sq, m);
  float nrm = sqrtf(sq);
  const float maxnorm = 1.0f - 4e-3f;
  if (nrm > maxnorm) mu = mu / nrm * maxnorm;
  out[b * 64 + j] = mu;
  out[256 + b * 64 + j] = lv;
}

extern "C" void kernel_launch(void* const* d_in, const int* in_sizes, int n_in,
                              void* d_out, int out_size, void* d_ws, size_t ws_size,
                              hipStream_t stream)
{
  const int* ei = (const int*)d_in[1];

  int*   ws_i    = (int*)d_ws;
  int*   dflag   = ws_i;                 // [0]
  int*   csr_row = ws_i + 256;           // 129
  int*   csr_src = ws_i + 512;           // 1152
  int*   csr_dst = ws_i + 2048;          // 1152
  float* FW   = (float*)d_ws;
  float* Wbuf = FW + FOFF_WBUF;
  float* ALS  = FW + FOFF_ALS;
  float* ALD  = FW + FOFF_ALD;
  float* MX   = FW + FOFF_MX;
  float* IDEN = FW + FOFF_IDEN;
  float* WE   = FW + FOFF_WE;
  float* XFp  = FW + FOFF_XFP;
  float* XBp  = FW + FOFF_XBP;
  float* HT   = FW + FOFF_HT;
  unsigned short* XSEQ = (unsigned short*)(FW + FOFF_XSEQ);
  unsigned short* Hb   = (unsigned short*)(FW + FOFF_H);
  unsigned short* Pb   = (unsigned short*)(FW + FOFF_P);
  unsigned int*   WT   = (unsigned int*)(FW + FOFF_WE);   // reuse WE region (dead after GAT2)

  // ---- dtype sniff + canonicalize inputs ----
  sniff_kernel<<<1, 256, 0, stream>>>((const unsigned short*)d_in[2], dflag);

  CvtArgs ca;
  static const int wsz[24] = {4096,256,256,256, 65536,256,256,256, 16384,64,64,64,
                              65536,262144,1024,1024, 65536,262144,1024,1024,
                              32768,64,32768,64};
  {
    int acc = 0;
    for (int k = 0; k < 24; ++k){ ca.src[k] = d_in[2 + k]; ca.off[k] = acc; acc += wsz[k]; }
    ca.off[24] = acc;  // WTOTAL
  }
  cvtw_kernel<<<(WTOTAL + 255) / 256, 256, 0, stream>>>(ca, dflag, Wbuf);
  cvtx_kernel<<<(NTOT * NFEAT) / 256, 256, 0, stream>>>(d_in[0], dflag, Pb);
  csr_kernel<<<1, 256, 0, stream>>>(ei, csr_row, csr_src, csr_dst);

  // ---- GAT layer 0: P[32768,16] @ g0W[16,256] -> H ----
  mm_kernel<0,1><<<dim3(512, 4), 256, 0, stream>>>(Pb, Wbuf + WOFF_G0W, Hb, NTOT, 256, 16);
  al_kernel<<<NTOT, 256, 0, stream>>>(Hb, Wbuf + WOFF_G0AS, Wbuf + WOFF_G0AD, ALS, ALD, 256, 4);
  mden_kernel<<<(NTOT * 4) / 256, 256, 0, stream>>>(ALS, ALD, csr_row, csr_src, MX, IDEN, 4);
  edgew_kernel<<<(NGRAPH * ESLOTS * 4) / 256, 256, 0, stream>>>(ALS, ALD, MX, IDEN, csr_src, csr_dst, WE, 4);
  agg_kernel<<<NTOT, 256, 0, stream>>>(Hb, WE, csr_row, csr_src, Wbuf + WOFF_G0B, Pb, 256, 4);

  // ---- GAT layer 1: P[32768,256] @ g1W[256,256] -> H ----
  mm_kernel<0,1><<<dim3(512, 4), 256, 0, stream>>>(Pb, Wbuf + WOFF_G1W, Hb, NTOT, 256, 256);
  al_kernel<<<NTOT, 256, 0, stream>>>(Hb, Wbuf + WOFF_G1AS, Wbuf + WOFF_G1AD, ALS, ALD, 256, 4);
  mden_kernel<<<(NTOT * 4) / 256, 256, 0, stream>>>(ALS, ALD, csr_row, csr_src, MX, IDEN, 4);
  edgew_kernel<<<(NGRAPH * ESLOTS * 4) / 256, 256, 0, stream>>>(ALS, ALD, MX, IDEN, csr_src, csr_dst, WE, 4);
  agg_kernel<<<NTOT, 256, 0, stream>>>(Hb, WE, csr_row, csr_src, Wbuf + WOFF_G1B, Pb, 256, 4);

  // ---- GAT layer 2: P[32768,256] @ g2W[256,64] -> H, 1 head ----
  mm_kernel<0,1><<<dim3(512, 1), 256, 0, stream>>>(Pb, Wbuf + WOFF_G2W, Hb, NTOT, 64, 256);
  al_kernel<<<NTOT, 64, 0, stream>>>(Hb, Wbuf + WOFF_G2AS, Wbuf + WOFF_G2AD, ALS, ALD, 64, 1);
  mden_kernel<<<NTOT / 256, 256, 0, stream>>>(ALS, ALD, csr_row, csr_src, MX, IDEN, 1);
  edgew_kernel<<<(NGRAPH * ESLOTS) / 256, 256, 0, stream>>>(ALS, ALD, MX, IDEN, csr_src, csr_dst, WE, 1);
  agg_kernel<<<NTOT, 64, 0, stream>>>(Hb, WE, csr_row, csr_src, Wbuf + WOFF_G2B, Pb, 64, 1);

  // ---- pool + LSTM input precompute ----
  pool_kernel<<<(NGRAPH * HIDD) / 256, 256, 0, stream>>>(Pb, XSEQ);
  mm_kernel<1,0><<<dim3(4, 16), 256, 0, stream>>>(XSEQ, Wbuf + WOFF_WIHF, XFp, 256, 1024, 64);
  mm_kernel<1,0><<<dim3(4, 16), 256, 0, stream>>>(XSEQ, Wbuf + WOFF_WIHB, XBp, 256, 1024, 64);

  // ---- pack Whh (WE region is dead now) + recurrence: 2 blocks = 2 directions ----
  packwhh_kernel<<<1024, 256, 0, stream>>>(Wbuf, WT);
  lstm2_kernel<<<2, 1024, 0, stream>>>(XFp, XBp, WT,
                                       Wbuf + WOFF_BIHF, Wbuf + WOFF_BHHF,
                                       Wbuf + WOFF_BIHB, Wbuf + WOFF_BHHB, HT);

  // ---- heads + projection ----
  head_kernel<<<1, 256, 0, stream>>>(HT, Wbuf + WOFF_MUW, Wbuf + WOFF_MUB,
                                     Wbuf + WOFF_LVW, Wbuf + WOFF_LVB, (float*)d_out);
}

// Round 5
// 909.060 us; speedup vs baseline: 2.5749x; 1.0182x over previous
//
#include <hip/hip_runtime.h>
#include <hip/hip_bf16.h>

// ---- problem constants ----
#define BSZ 4
#define TT 64
#define NNODE 128
#define NFEAT 16
#define HIDD 64
#define NHEAD 4
#define RHID 256
#define LDIM 64
#define EPG 1024
#define NGRAPH (BSZ*TT)          // 256
#define NTOT (NGRAPH*NNODE)      // 32768
#define ESLOTS (EPG+NNODE)       // 1152

// ---- canonical fp32 weight buffer offsets (floats) ----
#define WOFF_G0W 0
#define WOFF_G0AS 4096
#define WOFF_G0AD 4352
#define WOFF_G0B 4608
#define WOFF_G1W 4864
#define WOFF_G1AS 70400
#define WOFF_G1AD 70656
#define WOFF_G1B 70912
#define WOFF_G2W 71168
#define WOFF_G2AS 87552
#define WOFF_G2AD 87616
#define WOFF_G2B 87680
#define WOFF_WIHF 87744
#define WOFF_WHHF 153280
#define WOFF_BIHF 415424
#define WOFF_BHHF 416448
#define WOFF_WIHB 417472
#define WOFF_WHHB 483008
#define WOFF_BIHB 745152
#define WOFF_BHHB 746176
#define WOFF_MUW 747200
#define WOFF_MUB 779968
#define WOFF_LVW 780032
#define WOFF_LVB 812800
#define WTOTAL   812864

// ---- workspace float offsets ----
#define FOFF_WBUF 4096
#define FOFF_ALS  1052672
#define FOFF_ALD  1183744
#define FOFF_SYNC 1314816      // flags (16 ints) + HX (1024 uints)
#define FOFF_WE   1576960      // WT lives here
#define FOFF_XFP  2756608
#define FOFF_XBP  3018752
#define FOFF_HT   3280896
#define FOFF_XSEQ 3282944
#define FOFF_H    3291136
#define FOFF_P    7485440

__device__ __forceinline__ float b2f(unsigned short u){
  union { unsigned int i; float f; } v; v.i = ((unsigned int)u) << 16; return v.f;
}
__device__ __forceinline__ unsigned short f2b(float f){
  __hip_bfloat16 h = __float2bfloat16(f);
  union { __hip_bfloat16 h; unsigned short u; } v; v.h = h; return v.u;
}

// fused half2 dot: acc += w.x*h.x + w.y*h.y
__device__ __forceinline__ float dot2h(unsigned int w, unsigned int h, float acc){
#if __has_builtin(__builtin_amdgcn_fdot2)
  typedef _Float16 h2v __attribute__((ext_vector_type(2)));
  union { unsigned int u; h2v v; } a, b; a.u = w; b.u = h;
  return __builtin_amdgcn_fdot2(a.v, b.v, acc, false);
#else
  union { unsigned int u; _Float16 h[2]; } a, b; a.u = w; b.u = h;
  return acc + (float)a.h[0] * (float)b.h[0] + (float)a.h[1] * (float)b.h[1];
#endif
}

// ---------------- dtype sniff ----------------
__global__ void sniff_kernel(const unsigned short* __restrict__ w, int* __restrict__ flag){
  __shared__ int cnt;
  if (threadIdx.x == 0) cnt = 0;
  __syncthreads();
  int ok = 0;
  for (int i = threadIdx.x; i < 2048; i += 256){
    float a = fabsf(b2f(w[2 * i]));
    if (a > 1e-8f && a < 4.f) ok++;
  }
  atomicAdd(&cnt, ok);
  __syncthreads();
  if (threadIdx.x == 0) *flag = (cnt >= 1024) ? 1 : 0;
}

// ---------------- convert all float weights into one fp32 buffer ----------------
struct CvtArgs {
  const void* src[24];
  int off[25];
};
__global__ void cvtw_kernel(CvtArgs a, const int* __restrict__ flag, float* __restrict__ W){
  int t = blockIdx.x * blockDim.x + threadIdx.x;
  if (t >= WTOTAL) return;
  int k = 0;
  while (t >= a.off[k + 1]) ++k;
  int rel = t - a.off[k];
  float v;
  if (*flag) v = b2f(((const unsigned short*)a.src[k])[rel]);
  else       v = ((const float*)a.src[k])[rel];
  W[t] = v;
}

// ---------------- convert x -> bf16 ----------------
__global__ void cvtx_kernel(const void* __restrict__ x, const int* __restrict__ flag,
                            unsigned short* __restrict__ P){
  int i = blockIdx.x * blockDim.x + threadIdx.x;
  if (*flag) P[i] = ((const unsigned short*)x)[i];
  else       P[i] = f2b(((const float*)x)[i]);
}

// ---------------- CSR build ----------------
__global__ void csr_kernel(const int* __restrict__ ei, int* __restrict__ row,
                           int* __restrict__ colsrc, int* __restrict__ coldst){
  __shared__ int cnt[NNODE];
  __shared__ int off[NNODE];
  int tid = threadIdx.x;
  for (int i = tid; i < NNODE; i += blockDim.x) cnt[i] = 0;
  __syncthreads();
  for (int i = tid; i < ESLOTS; i += blockDim.x){
    int d = (i < EPG) ? ei[EPG + i] : (i - EPG);
    atomicAdd(&cnt[d], 1);
  }
  __syncthreads();
  if (tid == 0){
    int acc = 0;
    for (int i = 0; i < NNODE; ++i){ row[i] = acc; off[i] = acc; acc += cnt[i]; }
    row[NNODE] = acc;
  }
  __syncthreads();
  for (int i = tid; i < ESLOTS; i += blockDim.x){
    int s, d;
    if (i < EPG){ s = ei[i]; d = ei[EPG + i]; } else { s = i - EPG; d = i - EPG; }
    int pos = atomicAdd(&off[d], 1);
    colsrc[pos] = s; coldst[pos] = d;
  }
}

// ---------------- tiled matmul ----------------
template<int BT, int CBF16>
__global__ __launch_bounds__(256)
void mm_kernel(const unsigned short* __restrict__ A, const float* __restrict__ B,
               void* __restrict__ Cv, int M, int Nc, int K)
{
  __shared__ float As[16][68];
  __shared__ float Bs[16][68];
  const int tid = threadIdx.x;
  const int tx = tid & 15, ty = tid >> 4;
  const int m0 = blockIdx.x * 64, n0 = blockIdx.y * 64;
  float acc[4][4] = {};
  for (int kc = 0; kc < K; kc += 16){
    {
      int r = tid >> 2, kk0 = (tid & 3) << 2;
      uint2 u = *(const uint2*)(A + (size_t)(m0 + r) * K + kc + kk0);
      As[kk0+0][r] = b2f((unsigned short)(u.x & 0xffff));
      As[kk0+1][r] = b2f((unsigned short)(u.x >> 16));
      As[kk0+2][r] = b2f((unsigned short)(u.y & 0xffff));
      As[kk0+3][r] = b2f((unsigned short)(u.y >> 16));
    }
    if (BT == 0){
      int k = tid >> 4, c0 = (tid & 15) << 2;
      float4 bv = *(const float4*)(B + (size_t)(kc + k) * Nc + n0 + c0);
      Bs[k][c0+0] = bv.x; Bs[k][c0+1] = bv.y; Bs[k][c0+2] = bv.z; Bs[k][c0+3] = bv.w;
    } else {
      int n = tid >> 2, kk0 = (tid & 3) << 2;
      float4 bv = *(const float4*)(B + (size_t)(n0 + n) * K + kc + kk0);
      Bs[kk0+0][n] = bv.x; Bs[kk0+1][n] = bv.y; Bs[kk0+2][n] = bv.z; Bs[kk0+3][n] = bv.w;
    }
    __syncthreads();
    #pragma unroll
    for (int k = 0; k < 16; ++k){
      float4 av = *(const float4*)&As[k][ty << 2];
      float4 bv = *(const float4*)&Bs[k][tx << 2];
      float am[4] = {av.x, av.y, av.z, av.w};
      float bm[4] = {bv.x, bv.y, bv.z, bv.w};
      #pragma unroll
      for (int i = 0; i < 4; ++i)
        #pragma unroll
        for (int j = 0; j < 4; ++j) acc[i][j] += am[i] * bm[j];
    }
    __syncthreads();
  }
  if (CBF16){
    unsigned short* C = (unsigned short*)Cv;
    #pragma unroll
    for (int i = 0; i < 4; ++i){
      unsigned short* cp = C + (size_t)(m0 + (ty << 2) + i) * Nc + n0 + (tx << 2);
      #pragma unroll
      for (int j = 0; j < 4; ++j) cp[j] = f2b(acc[i][j]);
    }
  } else {
    float* C = (float*)Cv;
    #pragma unroll
    for (int i = 0; i < 4; ++i){
      float* cp = C + (size_t)(m0 + (ty << 2) + i) * Nc + n0 + (tx << 2);
      #pragma unroll
      for (int j = 0; j < 4; ++j) cp[j] = acc[i][j];
    }
  }
}

// ---------------- attention logits per (node, head) ----------------
__global__ void al_kernel(const unsigned short* __restrict__ H, const float* __restrict__ asrc,
                          const float* __restrict__ adst,
                          float* __restrict__ ALS, float* __restrict__ ALD, int HD, int Hh)
{
  int n = blockIdx.x;
  int tid = threadIdx.x;
  float hv = b2f(H[(size_t)n * HD + tid]);
  float vs = hv * asrc[tid];
  float vd = hv * adst[tid];
  #pragma unroll
  for (int m = 32; m >= 1; m >>= 1){ vs += __shfl_xor(vs, m); vd += __shfl_xor(vd, m); }
  if ((tid & 63) == 0){
    int h = tid >> 6;
    ALS[(size_t)n * Hh + h] = vs;
    ALD[(size_t)n * Hh + h] = vd;
  }
}

// ---------------- fused softmax+aggregate+bias+relu: block = dst node ----------------
// wave h = head h; online softmax over edges entirely in registers/shuffles.
__global__ void fagg_kernel(const unsigned short* __restrict__ H,
                            const float* __restrict__ ALS, const float* __restrict__ ALD,
                            const int* __restrict__ row, const int* __restrict__ colsrc,
                            const float* __restrict__ bias,
                            unsigned short* __restrict__ O, int HD, int Hh)
{
  int n = blockIdx.x, tid = threadIdx.x;
  int g = n >> 7, dn = n & 127;
  int h = tid >> 6, lane = tid & 63;
  int rs = row[dn], re = row[dn + 1];
  float aldv = ALD[(size_t)n * Hh + h];
  const float* ALSg = ALS + (size_t)g * NNODE * Hh;

  // phase 1: online max + denominator (all lanes of wave converge to same mx/den)
  float mx = -3e38f, den = 0.f;
  for (int base = rs; base < re; base += 64){
    int e = base + lane;
    float v = -3e38f;
    if (e < re){
      int s = colsrc[e];
      float t = ALSg[s * Hh + h] + aldv;
      v = t > 0.f ? t : 0.2f * t;
    }
    float mp = v;
    #pragma unroll
    for (int m = 32; m >= 1; m >>= 1) mp = fmaxf(mp, __shfl_xor(mp, m));
    float dp = (e < re) ? __expf(v - mp) : 0.f;
    #pragma unroll
    for (int m = 32; m >= 1; m >>= 1) dp += __shfl_xor(dp, m);
    if (mp > mx){ den = den * __expf(mx - mp) + dp; mx = mp; }
    else den += dp * __expf(mp - mx);
  }
  float iden = 1.f / (den + 1e-16f);

  // phase 2: weighted aggregation
  const unsigned short* Hg = H + (size_t)g * NNODE * HD;
  float acc = 0.f;
  for (int e = rs; e < re; ++e){
    int s = colsrc[e];
    float t = ALSg[s * Hh + h] + aldv;
    t = t > 0.f ? t : 0.2f * t;
    float w = __expf(t - mx) * iden;
    acc += w * b2f(Hg[(size_t)s * HD + tid]);
  }
  float o = acc + bias[tid];
  O[(size_t)n * HD + tid] = f2b(o > 0.f ? o : 0.f);
}

// ---------------- graph sum-pool -> seq layout [t][b][HIDD] (bf16) ----------------
__global__ void pool_kernel(const unsigned short* __restrict__ X3, unsigned short* __restrict__ XSEQ){
  int id = blockIdx.x * blockDim.x + threadIdx.x;
  if (id >= NGRAPH * HIDD) return;
  int g = id >> 6, f = id & 63;
  const unsigned short* p = X3 + (size_t)g * NNODE * HIDD + f;
  float s = 0.f;
  for (int dn = 0; dn < NNODE; ++dn) s += b2f(p[dn * HIDD]);
  int b = g >> 6, t = g & 63;
  XSEQ[(size_t)(t * BSZ + b) * HIDD + f] = f2b(s);
}

// ---------------- pack Whh into f16-pair, interleaved: WT[d][kk4][u][c] ----------------
__global__ void packwhh_kernel(const float* __restrict__ Wbuf, unsigned int* __restrict__ WT){
  int id = blockIdx.x * blockDim.x + threadIdx.x;   // < 262144
  int d = id >> 17;
  int r = id & 131071;
  int c = r & 3;
  int u = (r >> 2) & 1023;
  int kk4 = r >> 12;
  int kk = kk4 * 4 + c;
  const float* W = Wbuf + (d ? WOFF_WHHB : WOFF_WHHF);
  _Float16 a = (_Float16)W[u * RHID + 2 * kk];
  _Float16 b = (_Float16)W[u * RHID + 2 * kk + 1];
  union { _Float16 h; unsigned short s; } ua, ub; ua.h = a; ub.h = b;
  WT[id] = (unsigned int)ua.s | ((unsigned int)ub.s << 16);
}

// ---------------- LSTM, M-split: 8 WGs = 2 dirs x 4 unit-slices, LDS-resident weights ----
// WG (dir,m): units j in [64m,64m+64), all 4 gates, all 4 batches. 256 threads.
__global__ __launch_bounds__(256)
void lstm3_kernel(const float* __restrict__ XF, const float* __restrict__ XB,
                  const unsigned int* __restrict__ WT,
                  const float* __restrict__ bih_f, const float* __restrict__ bhh_f,
                  const float* __restrict__ bih_b, const float* __restrict__ bhh_b,
                  int* __restrict__ FLG, unsigned int* __restrict__ HX,
                  float* __restrict__ HT)
{
  __shared__ unsigned int WL[32][256][4];     // 128 KB weight slice
  __shared__ unsigned int h2u[4 * 128];       // full h, f16 pairs, [b][128]
  __shared__ float glds[4][64][4];            // [gate][unit][batch]
  __shared__ unsigned short hl[4][64];        // new h slice (f16)

  const int tid = threadIdx.x;
  const int m = blockIdx.x & 3, dir = blockIdx.x >> 2;
  const int gq = tid >> 6, jl = tid & 63;     // gate, local unit
  const int u = gq * 256 + 64 * m + jl;       // global gate-row
  const float* Xp = dir ? XB : XF;
  const float bias = (dir ? bih_b : bih_f)[u] + (dir ? bhh_b : bhh_f)[u];
  const int ub = tid >> 6, uj = tid & 63;     // updater: batch, unit (same split, reused)
  unsigned int* HXd = HX + dir * 512;
  int* FLGd = FLG + dir * 4;

  // preload weight slice: WL[kk4][tid] = WT[dir][kk4][u]
  {
    const uint4* WT4 = (const uint4*)(WT + (dir << 17));
    #pragma unroll
    for (int kk4 = 0; kk4 < 32; ++kk4)
      *(uint4*)WL[kk4][tid] = WT4[(kk4 << 10) + u];
  }
  for (int i = tid; i < 512; i += 256) h2u[i] = 0;
  float c = 0.f;
  __syncthreads();

  for (int t = 0; t < TT; ++t){
    const int tb = dir ? (TT - 1 - t) : t;
    const float* xr = Xp + (size_t)(tb * 4) * 1024 + u;
    float a0 = bias + xr[0];
    float a1 = bias + xr[1024];
    float a2 = bias + xr[2048];
    float a3 = bias + xr[3072];
    #pragma unroll 4
    for (int kk4 = 0; kk4 < 32; ++kk4){
      uint4 w4 = *(const uint4*)WL[kk4][tid];
      uint4 hb0 = *(const uint4*)&h2u[0 * 128 + (kk4 << 2)];
      uint4 hb1 = *(const uint4*)&h2u[1 * 128 + (kk4 << 2)];
      uint4 hb2 = *(const uint4*)&h2u[2 * 128 + (kk4 << 2)];
      uint4 hb3 = *(const uint4*)&h2u[3 * 128 + (kk4 << 2)];
      a0 = dot2h(w4.x, hb0.x, a0); a0 = dot2h(w4.y, hb0.y, a0);
      a0 = dot2h(w4.z, hb0.z, a0); a0 = dot2h(w4.w, hb0.w, a0);
      a1 = dot2h(w4.x, hb1.x, a1); a1 = dot2h(w4.y, hb1.y, a1);
      a1 = dot2h(w4.z, hb1.z, a1); a1 = dot2h(w4.w, hb1.w, a1);
      a2 = dot2h(w4.x, hb2.x, a2); a2 = dot2h(w4.y, hb2.y, a2);
      a2 = dot2h(w4.z, hb2.z, a2); a2 = dot2h(w4.w, hb2.w, a2);
      a3 = dot2h(w4.x, hb3.x, a3); a3 = dot2h(w4.y, hb3.y, a3);
      a3 = dot2h(w4.z, hb3.z, a3); a3 = dot2h(w4.w, hb3.w, a3);
    }
    glds[gq][jl][0] = a0; glds[gq][jl][1] = a1;
    glds[gq][jl][2] = a2; glds[gq][jl][3] = a3;
    __syncthreads();
    {
      float gi = glds[0][uj][ub];
      float gf = glds[1][uj][ub];
      float gg = glds[2][uj][ub];
      float go = glds[3][uj][ub];
      float si = 1.f / (1.f + __expf(-gi));
      float sf = 1.f / (1.f + __expf(-gf));
      float so = 1.f / (1.f + __expf(-go));
      float tg = 1.f - 2.f / (1.f + __expf(2.f * gg));
      c = sf * c + si * tg;
      float ch = 1.f - 2.f / (1.f + __expf(2.f * c));
      float hval = so * ch;
      union { _Float16 h; unsigned short s; } uh; uh.h = (_Float16)hval;
      hl[ub][uj] = uh.s;
      if (t == TT - 1) HT[(size_t)(dir * 4 + ub) * RHID + (64 * m + uj)] = hval;
    }
    __syncthreads();
    if (tid < 128){                 // pack + publish own slice: (b, pair)
      int b = tid >> 5, p = tid & 31;
      unsigned int v = (unsigned int)hl[b][2 * p] | ((unsigned int)hl[b][2 * p + 1] << 16);
      h2u[b * 128 + 32 * m + p] = v;
      HXd[b * 128 + 32 * m + p] = v;
    }
    __syncthreads();
    if (t == TT - 1) break;         // no exchange needed after last step
    if (tid == 0){
      __threadfence();
      __hip_atomic_store(&FLGd[m], t + 1, __ATOMIC_RELEASE, __HIP_MEMORY_SCOPE_AGENT);
      // poll peers
      for (int q = 0; q < 4; ++q){
        if (q == m) continue;
        int guard = 0;
        while (__hip_atomic_load(&FLGd[q], __ATOMIC_ACQUIRE, __HIP_MEMORY_SCOPE_AGENT) < t + 1
               && guard < 100000000){
          __builtin_amdgcn_s_sleep(8);
          ++guard;
        }
      }
      __threadfence();
    }
    __syncthreads();
    if (tid < 128){                 // fetch 3 peer slices (b, pair-of-96): map tid -> peer segment
      int b = tid >> 5, p = tid & 31;
      #pragma unroll
      for (int q = 0; q < 4; ++q){
        if (q == m) continue;
        h2u[b * 128 + 32 * q + p] = HXd[b * 128 + 32 * q + p];
      }
    }
    __syncthreads();
  }
}

// ---------------- heads + Poincare projection, fp32 out ----------------
__global__ void head_kernel(const float* __restrict__ HT,
                            const float* __restrict__ muW, const float* __restrict__ mub,
                            const float* __restrict__ lvW, const float* __restrict__ lvb,
                            float* __restrict__ out)
{
  int tid = threadIdx.x;            // 256
  int b = tid >> 6, j = tid & 63;
  const float* hf = HT + (size_t)b * RHID;
  const float* hb = HT + (size_t)(4 + b) * RHID;
  float mu = mub[j], lv = lvb[j];
  const float* mw = muW + (size_t)j * (2 * RHID);
  const float* lw = lvW + (size_t)j * (2 * RHID);
  for (int k = 0; k < RHID; ++k){
    float f0 = hf[k], f1 = hb[k];
    mu += f0 * mw[k] + f1 * mw[RHID + k];
    lv += f0 * lw[k] + f1 * lw[RHID + k];
  }
  float sq = mu * mu;
  #pragma unroll
  for (int m = 32; m >= 1; m >>= 1) sq += __shfl_xor(sq, m);
  float nrm = sqrtf(sq);
  const float maxnorm = 1.0f - 4e-3f;
  if (nrm > maxnorm) mu = mu / nrm * maxnorm;
  out[b * 64 + j] = mu;
  out[256 + b * 64 + j] = lv;
}

extern "C" void kernel_launch(void* const* d_in, const int* in_sizes, int n_in,
                              void* d_out, int out_size, void* d_ws, size_t ws_size,
                              hipStream_t stream)
{
  const int* ei = (const int*)d_in[1];

  int*   ws_i    = (int*)d_ws;
  int*   dflag   = ws_i;
  int*   csr_row = ws_i + 256;
  int*   csr_src = ws_i + 512;
  int*   csr_dst = ws_i + 2048;
  float* FW   = (float*)d_ws;
  float* Wbuf = FW + FOFF_WBUF;
  float* ALS  = FW + FOFF_ALS;
  float* ALD  = FW + FOFF_ALD;
  float* XFp  = FW + FOFF_XFP;
  float* XBp  = FW + FOFF_XBP;
  float* HT   = FW + FOFF_HT;
  unsigned short* XSEQ = (unsigned short*)(FW + FOFF_XSEQ);
  unsigned short* Hb   = (unsigned short*)(FW + FOFF_H);
  unsigned short* Pb   = (unsigned short*)(FW + FOFF_P);
  unsigned int*   WT   = (unsigned int*)(FW + FOFF_WE);
  int*            FLG  = (int*)(FW + FOFF_SYNC);
  unsigned int*   HX   = (unsigned int*)(FW + FOFF_SYNC + 16);

  // ---- dtype sniff + canonicalize inputs ----
  sniff_kernel<<<1, 256, 0, stream>>>((const unsigned short*)d_in[2], dflag);

  CvtArgs ca;
  static const int wsz[24] = {4096,256,256,256, 65536,256,256,256, 16384,64,64,64,
                              65536,262144,1024,1024, 65536,262144,1024,1024,
                              32768,64,32768,64};
  {
    int acc = 0;
    for (int k = 0; k < 24; ++k){ ca.src[k] = d_in[2 + k]; ca.off[k] = acc; acc += wsz[k]; }
    ca.off[24] = acc;
  }
  cvtw_kernel<<<(WTOTAL + 255) / 256, 256, 0, stream>>>(ca, dflag, Wbuf);
  cvtx_kernel<<<(NTOT * NFEAT) / 256, 256, 0, stream>>>(d_in[0], dflag, Pb);
  csr_kernel<<<1, 256, 0, stream>>>(ei, csr_row, csr_src, csr_dst);

  // ---- GAT layer 0 ----
  mm_kernel<0,1><<<dim3(512, 4), 256, 0, stream>>>(Pb, Wbuf + WOFF_G0W, Hb, NTOT, 256, 16);
  al_kernel<<<NTOT, 256, 0, stream>>>(Hb, Wbuf + WOFF_G0AS, Wbuf + WOFF_G0AD, ALS, ALD, 256, 4);
  fagg_kernel<<<NTOT, 256, 0, stream>>>(Hb, ALS, ALD, csr_row, csr_src, Wbuf + WOFF_G0B, Pb, 256, 4);

  // ---- GAT layer 1 ----
  mm_kernel<0,1><<<dim3(512, 4), 256, 0, stream>>>(Pb, Wbuf + WOFF_G1W, Hb, NTOT, 256, 256);
  al_kernel<<<NTOT, 256, 0, stream>>>(Hb, Wbuf + WOFF_G1AS, Wbuf + WOFF_G1AD, ALS, ALD, 256, 4);
  fagg_kernel<<<NTOT, 256, 0, stream>>>(Hb, ALS, ALD, csr_row, csr_src, Wbuf + WOFF_G1B, Pb, 256, 4);

  // ---- GAT layer 2 (1 head) ----
  mm_kernel<0,1><<<dim3(512, 1), 256, 0, stream>>>(Pb, Wbuf + WOFF_G2W, Hb, NTOT, 64, 256);
  al_kernel<<<NTOT, 64, 0, stream>>>(Hb, Wbuf + WOFF_G2AS, Wbuf + WOFF_G2AD, ALS, ALD, 64, 1);
  fagg_kernel<<<NTOT, 64, 0, stream>>>(Hb, ALS, ALD, csr_row, csr_src, Wbuf + WOFF_G2B, Pb, 64, 1);

  // ---- pool + LSTM input precompute ----
  pool_kernel<<<(NGRAPH * HIDD) / 256, 256, 0, stream>>>(Pb, XSEQ);
  mm_kernel<1,0><<<dim3(4, 16), 256, 0, stream>>>(XSEQ, Wbuf + WOFF_WIHF, XFp, 256, 1024, 64);
  mm_kernel<1,0><<<dim3(4, 16), 256, 0, stream>>>(XSEQ, Wbuf + WOFF_WIHB, XBp, 256, 1024, 64);

  // ---- pack + LSTM (8 WGs, flag region zeroed first — capture-legal) ----
  packwhh_kernel<<<1024, 256, 0, stream>>>(Wbuf, WT);
  hipMemsetAsync((void*)FLG, 0, 64, stream);
  lstm3_kernel<<<8, 256, 0, stream>>>(XFp, XBp, WT,
                                      Wbuf + WOFF_BIHF, Wbuf + WOFF_BHHF,
                                      Wbuf + WOFF_BIHB, Wbuf + WOFF_BHHB,
                                      FLG, HX, HT);

  // ---- heads + projection ----
  head_kernel<<<1, 256, 0, stream>>>(HT, Wbuf + WOFF_MUW, Wbuf + WOFF_MUB,
                                     Wbuf + WOFF_LVW, Wbuf + WOFF_LVB, (float*)d_out);
}

// Round 6
// 876.377 us; speedup vs baseline: 2.6709x; 1.0373x over previous
//
#include <hip/hip_runtime.h>
#include <hip/hip_bf16.h>

// ---- problem constants ----
#define BSZ 4
#define TT 64
#define NNODE 128
#define NFEAT 16
#define HIDD 64
#define NHEAD 4
#define RHID 256
#define LDIM 64
#define EPG 1024
#define NGRAPH (BSZ*TT)          // 256
#define NTOT (NGRAPH*NNODE)      // 32768
#define ESLOTS (EPG+NNODE)       // 1152

// ---- canonical fp32 weight buffer offsets (floats) ----
#define WOFF_G0W 0
#define WOFF_G0AS 4096
#define WOFF_G0AD 4352
#define WOFF_G0B 4608
#define WOFF_G1W 4864
#define WOFF_G1AS 70400
#define WOFF_G1AD 70656
#define WOFF_G1B 70912
#define WOFF_G2W 71168
#define WOFF_G2AS 87552
#define WOFF_G2AD 87616
#define WOFF_G2B 87680
#define WOFF_WIHF 87744
#define WOFF_WHHF 153280
#define WOFF_BIHF 415424
#define WOFF_BHHF 416448
#define WOFF_WIHB 417472
#define WOFF_WHHB 483008
#define WOFF_BIHB 745152
#define WOFF_BHHB 746176
#define WOFF_MUW 747200
#define WOFF_MUB 779968
#define WOFF_LVW 780032
#define WOFF_LVB 812800
#define WTOTAL   812864

// ---- workspace float offsets ----
#define FOFF_WBUF 4096
#define FOFF_ALS  1052672
#define FOFF_ALD  1183744
#define FOFF_SYNC 1314816      // CNT (128 ints) + HX (2048 uints, double-buffered)
#define FOFF_WE   1576960      // WT lives here
#define FOFF_XFP  2756608
#define FOFF_XBP  3018752
#define FOFF_HT   3280896
#define FOFF_XSEQ 3282944
#define FOFF_H    3291136
#define FOFF_P    7485440

__device__ __forceinline__ float b2f(unsigned short u){
  union { unsigned int i; float f; } v; v.i = ((unsigned int)u) << 16; return v.f;
}
__device__ __forceinline__ unsigned short f2b(float f){
  __hip_bfloat16 h = __float2bfloat16(f);
  union { __hip_bfloat16 h; unsigned short u; } v; v.h = h; return v.u;
}

// fused half2 dot: acc += w.x*h.x + w.y*h.y
__device__ __forceinline__ float dot2h(unsigned int w, unsigned int h, float acc){
#if __has_builtin(__builtin_amdgcn_fdot2)
  typedef _Float16 h2v __attribute__((ext_vector_type(2)));
  union { unsigned int u; h2v v; } a, b; a.u = w; b.u = h;
  return __builtin_amdgcn_fdot2(a.v, b.v, acc, false);
#else
  union { unsigned int u; _Float16 h[2]; } a, b; a.u = w; b.u = h;
  return acc + (float)a.h[0] * (float)b.h[0] + (float)a.h[1] * (float)b.h[1];
#endif
}

// ---------------- dtype sniff ----------------
__global__ void sniff_kernel(const unsigned short* __restrict__ w, int* __restrict__ flag){
  __shared__ int cnt;
  if (threadIdx.x == 0) cnt = 0;
  __syncthreads();
  int ok = 0;
  for (int i = threadIdx.x; i < 2048; i += 256){
    float a = fabsf(b2f(w[2 * i]));
    if (a > 1e-8f && a < 4.f) ok++;
  }
  atomicAdd(&cnt, ok);
  __syncthreads();
  if (threadIdx.x == 0) *flag = (cnt >= 1024) ? 1 : 0;
}

// ---------------- convert all float weights into one fp32 buffer ----------------
struct CvtArgs {
  const void* src[24];
  int off[25];
};
__global__ void cvtw_kernel(CvtArgs a, const int* __restrict__ flag, float* __restrict__ W){
  int t = blockIdx.x * blockDim.x + threadIdx.x;
  if (t >= WTOTAL) return;
  int k = 0;
  while (t >= a.off[k + 1]) ++k;
  int rel = t - a.off[k];
  float v;
  if (*flag) v = b2f(((const unsigned short*)a.src[k])[rel]);
  else       v = ((const float*)a.src[k])[rel];
  W[t] = v;
}

// ---------------- convert x -> bf16 ----------------
__global__ void cvtx_kernel(const void* __restrict__ x, const int* __restrict__ flag,
                            unsigned short* __restrict__ P){
  int i = blockIdx.x * blockDim.x + threadIdx.x;
  if (*flag) P[i] = ((const unsigned short*)x)[i];
  else       P[i] = f2b(((const float*)x)[i]);
}

// ---------------- CSR build ----------------
__global__ void csr_kernel(const int* __restrict__ ei, int* __restrict__ row,
                           int* __restrict__ colsrc, int* __restrict__ coldst){
  __shared__ int cnt[NNODE];
  __shared__ int off[NNODE];
  int tid = threadIdx.x;
  for (int i = tid; i < NNODE; i += blockDim.x) cnt[i] = 0;
  __syncthreads();
  for (int i = tid; i < ESLOTS; i += blockDim.x){
    int d = (i < EPG) ? ei[EPG + i] : (i - EPG);
    atomicAdd(&cnt[d], 1);
  }
  __syncthreads();
  if (tid == 0){
    int acc = 0;
    for (int i = 0; i < NNODE; ++i){ row[i] = acc; off[i] = acc; acc += cnt[i]; }
    row[NNODE] = acc;
  }
  __syncthreads();
  for (int i = tid; i < ESLOTS; i += blockDim.x){
    int s, d;
    if (i < EPG){ s = ei[i]; d = ei[EPG + i]; } else { s = i - EPG; d = i - EPG; }
    int pos = atomicAdd(&off[d], 1);
    colsrc[pos] = s; coldst[pos] = d;
  }
}

// ---------------- tiled matmul ----------------
template<int BT, int CBF16>
__global__ __launch_bounds__(256)
void mm_kernel(const unsigned short* __restrict__ A, const float* __restrict__ B,
               void* __restrict__ Cv, int M, int Nc, int K)
{
  __shared__ float As[16][68];
  __shared__ float Bs[16][68];
  const int tid = threadIdx.x;
  const int tx = tid & 15, ty = tid >> 4;
  const int m0 = blockIdx.x * 64, n0 = blockIdx.y * 64;
  float acc[4][4] = {};
  for (int kc = 0; kc < K; kc += 16){
    {
      int r = tid >> 2, kk0 = (tid & 3) << 2;
      uint2 u = *(const uint2*)(A + (size_t)(m0 + r) * K + kc + kk0);
      As[kk0+0][r] = b2f((unsigned short)(u.x & 0xffff));
      As[kk0+1][r] = b2f((unsigned short)(u.x >> 16));
      As[kk0+2][r] = b2f((unsigned short)(u.y & 0xffff));
      As[kk0+3][r] = b2f((unsigned short)(u.y >> 16));
    }
    if (BT == 0){
      int k = tid >> 4, c0 = (tid & 15) << 2;
      float4 bv = *(const float4*)(B + (size_t)(kc + k) * Nc + n0 + c0);
      Bs[k][c0+0] = bv.x; Bs[k][c0+1] = bv.y; Bs[k][c0+2] = bv.z; Bs[k][c0+3] = bv.w;
    } else {
      int n = tid >> 2, kk0 = (tid & 3) << 2;
      float4 bv = *(const float4*)(B + (size_t)(n0 + n) * K + kc + kk0);
      Bs[kk0+0][n] = bv.x; Bs[kk0+1][n] = bv.y; Bs[kk0+2][n] = bv.z; Bs[kk0+3][n] = bv.w;
    }
    __syncthreads();
    #pragma unroll
    for (int k = 0; k < 16; ++k){
      float4 av = *(const float4*)&As[k][ty << 2];
      float4 bv = *(const float4*)&Bs[k][tx << 2];
      float am[4] = {av.x, av.y, av.z, av.w};
      float bm[4] = {bv.x, bv.y, bv.z, bv.w};
      #pragma unroll
      for (int i = 0; i < 4; ++i)
        #pragma unroll
        for (int j = 0; j < 4; ++j) acc[i][j] += am[i] * bm[j];
    }
    __syncthreads();
  }
  if (CBF16){
    unsigned short* C = (unsigned short*)Cv;
    #pragma unroll
    for (int i = 0; i < 4; ++i){
      unsigned short* cp = C + (size_t)(m0 + (ty << 2) + i) * Nc + n0 + (tx << 2);
      #pragma unroll
      for (int j = 0; j < 4; ++j) cp[j] = f2b(acc[i][j]);
    }
  } else {
    float* C = (float*)Cv;
    #pragma unroll
    for (int i = 0; i < 4; ++i){
      float* cp = C + (size_t)(m0 + (ty << 2) + i) * Nc + n0 + (tx << 2);
      #pragma unroll
      for (int j = 0; j < 4; ++j) cp[j] = acc[i][j];
    }
  }
}

// ---------------- attention logits per (node, head) ----------------
__global__ void al_kernel(const unsigned short* __restrict__ H, const float* __restrict__ asrc,
                          const float* __restrict__ adst,
                          float* __restrict__ ALS, float* __restrict__ ALD, int HD, int Hh)
{
  int n = blockIdx.x;
  int tid = threadIdx.x;
  float hv = b2f(H[(size_t)n * HD + tid]);
  float vs = hv * asrc[tid];
  float vd = hv * adst[tid];
  #pragma unroll
  for (int m = 32; m >= 1; m >>= 1){ vs += __shfl_xor(vs, m); vd += __shfl_xor(vd, m); }
  if ((tid & 63) == 0){
    int h = tid >> 6;
    ALS[(size_t)n * Hh + h] = vs;
    ALD[(size_t)n * Hh + h] = vd;
  }
}

// ---------------- fused softmax+aggregate+bias+relu: block = dst node ----------------
__global__ void fagg_kernel(const unsigned short* __restrict__ H,
                            const float* __restrict__ ALS, const float* __restrict__ ALD,
                            const int* __restrict__ row, const int* __restrict__ colsrc,
                            const float* __restrict__ bias,
                            unsigned short* __restrict__ O, int HD, int Hh)
{
  int n = blockIdx.x, tid = threadIdx.x;
  int g = n >> 7, dn = n & 127;
  int h = tid >> 6, lane = tid & 63;
  int rs = row[dn], re = row[dn + 1];
  float aldv = ALD[(size_t)n * Hh + h];
  const float* ALSg = ALS + (size_t)g * NNODE * Hh;

  float mx = -3e38f, den = 0.f;
  for (int base = rs; base < re; base += 64){
    int e = base + lane;
    float v = -3e38f;
    if (e < re){
      int s = colsrc[e];
      float t = ALSg[s * Hh + h] + aldv;
      v = t > 0.f ? t : 0.2f * t;
    }
    float mp = v;
    #pragma unroll
    for (int m = 32; m >= 1; m >>= 1) mp = fmaxf(mp, __shfl_xor(mp, m));
    float dp = (e < re) ? __expf(v - mp) : 0.f;
    #pragma unroll
    for (int m = 32; m >= 1; m >>= 1) dp += __shfl_xor(dp, m);
    if (mp > mx){ den = den * __expf(mx - mp) + dp; mx = mp; }
    else den += dp * __expf(mp - mx);
  }
  float iden = 1.f / (den + 1e-16f);

  const unsigned short* Hg = H + (size_t)g * NNODE * HD;
  float acc = 0.f;
  for (int e = rs; e < re; ++e){
    int s = colsrc[e];
    float t = ALSg[s * Hh + h] + aldv;
    t = t > 0.f ? t : 0.2f * t;
    float w = __expf(t - mx) * iden;
    acc += w * b2f(Hg[(size_t)s * HD + tid]);
  }
  float o = acc + bias[tid];
  O[(size_t)n * HD + tid] = f2b(o > 0.f ? o : 0.f);
}

// ---------------- graph sum-pool -> seq layout [t][b][HIDD] (bf16) ----------------
__global__ void pool_kernel(const unsigned short* __restrict__ X3, unsigned short* __restrict__ XSEQ){
  int id = blockIdx.x * blockDim.x + threadIdx.x;
  if (id >= NGRAPH * HIDD) return;
  int g = id >> 6, f = id & 63;
  const unsigned short* p = X3 + (size_t)g * NNODE * HIDD + f;
  float s = 0.f;
  for (int dn = 0; dn < NNODE; ++dn) s += b2f(p[dn * HIDD]);
  int b = g >> 6, t = g & 63;
  XSEQ[(size_t)(t * BSZ + b) * HIDD + f] = f2b(s);
}

// ---------------- pack Whh into f16-pair, interleaved: WT[d][kk4][u][c] ----------------
__global__ void packwhh_kernel(const float* __restrict__ Wbuf, unsigned int* __restrict__ WT){
  int id = blockIdx.x * blockDim.x + threadIdx.x;   // < 262144
  int d = id >> 17;
  int r = id & 131071;
  int c = r & 3;
  int u = (r >> 2) & 1023;
  int kk4 = r >> 12;
  int kk = kk4 * 4 + c;
  const float* W = Wbuf + (d ? WOFF_WHHB : WOFF_WHHF);
  _Float16 a = (_Float16)W[u * RHID + 2 * kk];
  _Float16 b = (_Float16)W[u * RHID + 2 * kk + 1];
  union { _Float16 h; unsigned short s; } ua, ub; ua.h = a; ub.h = b;
  WT[id] = (unsigned int)ua.s | ((unsigned int)ub.s << 16);
}

// ---------------- LSTM, M-split, lean per-step counter sync ----------------
// 8 WGs = 2 dirs x 4 unit-slices; 256 threads each; 128 KB LDS-resident weights.
// CNT[dir][t]: monotonic per-step counters (memset 0). HX double-buffered by t&1.
__global__ __launch_bounds__(256)
void lstm5_kernel(const float* __restrict__ XF, const float* __restrict__ XB,
                  const unsigned int* __restrict__ WT,
                  const float* __restrict__ bih_f, const float* __restrict__ bhh_f,
                  const float* __restrict__ bih_b, const float* __restrict__ bhh_b,
                  int* __restrict__ CNT, unsigned int* __restrict__ HX,
                  float* __restrict__ HT)
{
  __shared__ unsigned int WL[32][256][4];     // 128 KB weight slice
  __shared__ unsigned int h2u[4 * 128];       // full h, f16 pairs, [b][128]
  __shared__ float glds[4][64][5];            // [gate][unit][batch] (pad 5: conflict-free)
  __shared__ unsigned short hl[4][64];        // new h slice (f16)

  const int tid = threadIdx.x;
  const int m = blockIdx.x & 3, dir = blockIdx.x >> 2;
  const int gq = tid >> 6, jl = tid & 63;
  const int u = gq * 256 + 64 * m + jl;
  const float* Xp = dir ? XB : XF;
  const float bias = (dir ? bih_b : bih_f)[u] + (dir ? bhh_b : bhh_f)[u];
  const int ub = tid >> 6, uj = tid & 63;
  int* CNTd = CNT + dir * 64;
  unsigned int* HXd = HX + dir * 1024;        // [slot][512]

  {
    const uint4* WT4 = (const uint4*)(WT + (dir << 17));
    #pragma unroll
    for (int kk4 = 0; kk4 < 32; ++kk4)
      *(uint4*)WL[kk4][tid] = WT4[(kk4 << 10) + u];
  }
  for (int i = tid; i < 512; i += 256) h2u[i] = 0;
  float c = 0.f;
  __syncthreads();

  for (int t = 0; t < TT; ++t){
    const int tb = dir ? (TT - 1 - t) : t;
    const float* xr = Xp + (size_t)(tb * 4) * 1024 + u;
    float a0 = bias + xr[0];
    float a1 = bias + xr[1024];
    float a2 = bias + xr[2048];
    float a3 = bias + xr[3072];
    #pragma unroll 4
    for (int kk4 = 0; kk4 < 32; ++kk4){
      uint4 w4 = *(const uint4*)WL[kk4][tid];
      uint4 hb0 = *(const uint4*)&h2u[0 * 128 + (kk4 << 2)];
      uint4 hb1 = *(const uint4*)&h2u[1 * 128 + (kk4 << 2)];
      uint4 hb2 = *(const uint4*)&h2u[2 * 128 + (kk4 << 2)];
      uint4 hb3 = *(const uint4*)&h2u[3 * 128 + (kk4 << 2)];
      a0 = dot2h(w4.x, hb0.x, a0); a0 = dot2h(w4.y, hb0.y, a0);
      a0 = dot2h(w4.z, hb0.z, a0); a0 = dot2h(w4.w, hb0.w, a0);
      a1 = dot2h(w4.x, hb1.x, a1); a1 = dot2h(w4.y, hb1.y, a1);
      a1 = dot2h(w4.z, hb1.z, a1); a1 = dot2h(w4.w, hb1.w, a1);
      a2 = dot2h(w4.x, hb2.x, a2); a2 = dot2h(w4.y, hb2.y, a2);
      a2 = dot2h(w4.z, hb2.z, a2); a2 = dot2h(w4.w, hb2.w, a2);
      a3 = dot2h(w4.x, hb3.x, a3); a3 = dot2h(w4.y, hb3.y, a3);
      a3 = dot2h(w4.z, hb3.z, a3); a3 = dot2h(w4.w, hb3.w, a3);
    }
    glds[gq][jl][0] = a0; glds[gq][jl][1] = a1;
    glds[gq][jl][2] = a2; glds[gq][jl][3] = a3;
    __syncthreads();
    {
      float gi = glds[0][uj][ub];
      float gf = glds[1][uj][ub];
      float gg = glds[2][uj][ub];
      float go = glds[3][uj][ub];
      float si = 1.f / (1.f + __expf(-gi));
      float sf = 1.f / (1.f + __expf(-gf));
      float so = 1.f / (1.f + __expf(-go));
      float tg = 1.f - 2.f / (1.f + __expf(2.f * gg));
      c = sf * c + si * tg;
      float ch = 1.f - 2.f / (1.f + __expf(2.f * c));
      float hval = so * ch;
      union { _Float16 h; unsigned short s; } uh; uh.h = (_Float16)hval;
      hl[ub][uj] = uh.s;
      if (t == TT - 1) HT[(size_t)(dir * 4 + ub) * RHID + (64 * m + uj)] = hval;
    }
    __syncthreads();
    if (t == TT - 1) break;

    unsigned int* HXs = HXd + (t & 1) * 512;
    if (tid < 128){                 // pack + publish own slice
      int b = tid >> 5, p = tid & 31;
      unsigned int v = (unsigned int)hl[b][2 * p] | ((unsigned int)hl[b][2 * p + 1] << 16);
      h2u[b * 128 + 32 * m + p] = v;
      __hip_atomic_store(&HXs[b * 128 + 32 * m + p], v,
                         __ATOMIC_RELAXED, __HIP_MEMORY_SCOPE_AGENT);
    }
    __syncthreads();                // drains publishers' stores (vmcnt) before the release
    if (tid == 0)
      __hip_atomic_fetch_add(&CNTd[t], 1, __ATOMIC_RELEASE, __HIP_MEMORY_SCOPE_AGENT);
    if (tid < 128){                 // wait for all 4 WGs, fetch 3 peer slices
      int b = tid >> 5, p = tid & 31;
      int guard = 0;
      while (__hip_atomic_load(&CNTd[t], __ATOMIC_ACQUIRE, __HIP_MEMORY_SCOPE_AGENT) < 4
             && guard < 100000000){
        __builtin_amdgcn_s_sleep(1);
        ++guard;
      }
      #pragma unroll
      for (int q = 0; q < 4; ++q){
        if (q == m) continue;
        h2u[b * 128 + 32 * q + p] =
          __hip_atomic_load(&HXs[b * 128 + 32 * q + p],
                            __ATOMIC_RELAXED, __HIP_MEMORY_SCOPE_AGENT);
      }
    }
    __syncthreads();
  }
}

// ---------------- heads + Poincare projection, fp32 out ----------------
__global__ void head_kernel(const float* __restrict__ HT,
                            const float* __restrict__ muW, const float* __restrict__ mub,
                            const float* __restrict__ lvW, const float* __restrict__ lvb,
                            float* __restrict__ out)
{
  int tid = threadIdx.x;            // 256
  int b = tid >> 6, j = tid & 63;
  const float* hf = HT + (size_t)b * RHID;
  const float* hb = HT + (size_t)(4 + b) * RHID;
  float mu = mub[j], lv = lvb[j];
  const float* mw = muW + (size_t)j * (2 * RHID);
  const float* lw = lvW + (size_t)j * (2 * RHID);
  for (int k = 0; k < RHID; ++k){
    float f0 = hf[k], f1 = hb[k];
    mu += f0 * mw[k] + f1 * mw[RHID + k];
    lv += f0 * lw[k] + f1 * lw[RHID + k];
  }
  float sq = mu * mu;
  #pragma unroll
  for (int m = 32; m >= 1; m >>= 1) sq += __shfl_xor(sq, m);
  float nrm = sqrtf(sq);
  const float maxnorm = 1.0f - 4e-3f;
  if (nrm > maxnorm) mu = mu / nrm * maxnorm;
  out[b * 64 + j] = mu;
  out[256 + b * 64 + j] = lv;
}

extern "C" void kernel_launch(void* const* d_in, const int* in_sizes, int n_in,
                              void* d_out, int out_size, void* d_ws, size_t ws_size,
                              hipStream_t stream)
{
  const int* ei = (const int*)d_in[1];

  int*   ws_i    = (int*)d_ws;
  int*   dflag   = ws_i;
  int*   csr_row = ws_i + 256;
  int*   csr_src = ws_i + 512;
  int*   csr_dst = ws_i + 2048;
  float* FW   = (float*)d_ws;
  float* Wbuf = FW + FOFF_WBUF;
  float* ALS  = FW + FOFF_ALS;
  float* ALD  = FW + FOFF_ALD;
  float* XFp  = FW + FOFF_XFP;
  float* XBp  = FW + FOFF_XBP;
  float* HT   = FW + FOFF_HT;
  unsigned short* XSEQ = (unsigned short*)(FW + FOFF_XSEQ);
  unsigned short* Hb   = (unsigned short*)(FW + FOFF_H);
  unsigned short* Pb   = (unsigned short*)(FW + FOFF_P);
  unsigned int*   WT   = (unsigned int*)(FW + FOFF_WE);
  int*            CNT  = (int*)(FW + FOFF_SYNC);                 // 128 ints
  unsigned int*   HX   = (unsigned int*)(FW + FOFF_SYNC + 128);  // 2048 uints

  // ---- dtype sniff + canonicalize inputs ----
  sniff_kernel<<<1, 256, 0, stream>>>((const unsigned short*)d_in[2], dflag);

  CvtArgs ca;
  static const int wsz[24] = {4096,256,256,256, 65536,256,256,256, 16384,64,64,64,
                              65536,262144,1024,1024, 65536,262144,1024,1024,
                              32768,64,32768,64};
  {
    int acc = 0;
    for (int k = 0; k < 24; ++k){ ca.src[k] = d_in[2 + k]; ca.off[k] = acc; acc += wsz[k]; }
    ca.off[24] = acc;
  }
  cvtw_kernel<<<(WTOTAL + 255) / 256, 256, 0, stream>>>(ca, dflag, Wbuf);
  cvtx_kernel<<<(NTOT * NFEAT) / 256, 256, 0, stream>>>(d_in[0], dflag, Pb);
  csr_kernel<<<1, 256, 0, stream>>>(ei, csr_row, csr_src, csr_dst);

  // ---- GAT layer 0 ----
  mm_kernel<0,1><<<dim3(512, 4), 256, 0, stream>>>(Pb, Wbuf + WOFF_G0W, Hb, NTOT, 256, 16);
  al_kernel<<<NTOT, 256, 0, stream>>>(Hb, Wbuf + WOFF_G0AS, Wbuf + WOFF_G0AD, ALS, ALD, 256, 4);
  fagg_kernel<<<NTOT, 256, 0, stream>>>(Hb, ALS, ALD, csr_row, csr_src, Wbuf + WOFF_G0B, Pb, 256, 4);

  // ---- GAT layer 1 ----
  mm_kernel<0,1><<<dim3(512, 4), 256, 0, stream>>>(Pb, Wbuf + WOFF_G1W, Hb, NTOT, 256, 256);
  al_kernel<<<NTOT, 256, 0, stream>>>(Hb, Wbuf + WOFF_G1AS, Wbuf + WOFF_G1AD, ALS, ALD, 256, 4);
  fagg_kernel<<<NTOT, 256, 0, stream>>>(Hb, ALS, ALD, csr_row, csr_src, Wbuf + WOFF_G1B, Pb, 256, 4);

  // ---- GAT layer 2 (1 head) ----
  mm_kernel<0,1><<<dim3(512, 1), 256, 0, stream>>>(Pb, Wbuf + WOFF_G2W, Hb, NTOT, 64, 256);
  al_kernel<<<NTOT, 64, 0, stream>>>(Hb, Wbuf + WOFF_G2AS, Wbuf + WOFF_G2AD, ALS, ALD, 64, 1);
  fagg_kernel<<<NTOT, 64, 0, stream>>>(Hb, ALS, ALD, csr_row, csr_src, Wbuf + WOFF_G2B, Pb, 64, 1);

  // ---- pool + LSTM input precompute ----
  pool_kernel<<<(NGRAPH * HIDD) / 256, 256, 0, stream>>>(Pb, XSEQ);
  mm_kernel<1,0><<<dim3(4, 16), 256, 0, stream>>>(XSEQ, Wbuf + WOFF_WIHF, XFp, 256, 1024, 64);
  mm_kernel<1,0><<<dim3(4, 16), 256, 0, stream>>>(XSEQ, Wbuf + WOFF_WIHB, XBp, 256, 1024, 64);

  // ---- pack + LSTM (8 WGs, counter region zeroed first — capture-legal) ----
  packwhh_kernel<<<1024, 256, 0, stream>>>(Wbuf, WT);
  hipMemsetAsync((void*)CNT, 0, 512, stream);
  lstm5_kernel<<<8, 256, 0, stream>>>(XFp, XBp, WT,
                                      Wbuf + WOFF_BIHF, Wbuf + WOFF_BHHF,
                                      Wbuf + WOFF_BIHB, Wbuf + WOFF_BHHB,
                                      CNT, HX, HT);

  // ---- heads + projection ----
  head_kernel<<<1, 256, 0, stream>>>(HT, Wbuf + WOFF_MUW, Wbuf + WOFF_MUB,
                                     Wbuf + WOFF_LVW, Wbuf + WOFF_LVB, (float*)d_out);
}

// Round 7
// 777.395 us; speedup vs baseline: 3.0110x; 1.1273x over previous
//
#include <hip/hip_runtime.h>
#include <hip/hip_bf16.h>

// ---- problem constants ----
#define BSZ 4
#define TT 64
#define NNODE 128
#define NFEAT 16
#define HIDD 64
#define NHEAD 4
#define RHID 256
#define LDIM 64
#define EPG 1024
#define NGRAPH (BSZ*TT)          // 256
#define NTOT (NGRAPH*NNODE)      // 32768
#define ESLOTS (EPG+NNODE)       // 1152

// ---- canonical fp32 weight buffer offsets (floats) ----
#define WOFF_G0W 0
#define WOFF_G0AS 4096
#define WOFF_G0AD 4352
#define WOFF_G0B 4608
#define WOFF_G1W 4864
#define WOFF_G1AS 70400
#define WOFF_G1AD 70656
#define WOFF_G1B 70912
#define WOFF_G2W 71168
#define WOFF_G2AS 87552
#define WOFF_G2AD 87616
#define WOFF_G2B 87680
#define WOFF_WIHF 87744
#define WOFF_WHHF 153280
#define WOFF_BIHF 415424
#define WOFF_BHHF 416448
#define WOFF_WIHB 417472
#define WOFF_WHHB 483008
#define WOFF_BIHB 745152
#define WOFF_BHHB 746176
#define WOFF_MUW 747200
#define WOFF_MUB 779968
#define WOFF_LVW 780032
#define WOFF_LVB 812800
#define WTOTAL   812864

// ---- workspace float offsets ----
#define FOFF_WBUF 4096
#define FOFF_ALS  1052672
#define FOFF_ALD  1183744
#define FOFF_SYNC 1314816      // FLG (512 ints) + HX (2048 uints, double-buffered)
#define FOFF_WE   1576960      // WT lives here
#define FOFF_BBF  1900000      // bf16 B matrices (u16 view)
#define FOFF_XFP  2756608
#define FOFF_XBP  3018752
#define FOFF_HT   3280896
#define FOFF_XSEQ 3282944
#define FOFF_H    3291136
#define FOFF_P    7485440

// bf16 B-matrix u16 offsets inside BBF
#define BOFF_G0 0
#define BOFF_G1 4096
#define BOFF_G2 69632
#define BOFF_WF 86016
#define BOFF_WB 151552
#define BTOTAL  217088

typedef __attribute__((ext_vector_type(8))) short short8;
typedef __attribute__((ext_vector_type(4))) float float4v;

__device__ __forceinline__ float b2f(unsigned short u){
  union { unsigned int i; float f; } v; v.i = ((unsigned int)u) << 16; return v.f;
}
__device__ __forceinline__ unsigned short f2b(float f){
  __hip_bfloat16 h = __float2bfloat16(f);
  union { __hip_bfloat16 h; unsigned short u; } v; v.h = h; return v.u;
}

// fused half2 dot: acc += w.x*h.x + w.y*h.y
__device__ __forceinline__ float dot2h(unsigned int w, unsigned int h, float acc){
#if __has_builtin(__builtin_amdgcn_fdot2)
  typedef _Float16 h2v __attribute__((ext_vector_type(2)));
  union { unsigned int u; h2v v; } a, b; a.u = w; b.u = h;
  return __builtin_amdgcn_fdot2(a.v, b.v, acc, false);
#else
  union { unsigned int u; _Float16 h[2]; } a, b; a.u = w; b.u = h;
  return acc + (float)a.h[0] * (float)b.h[0] + (float)a.h[1] * (float)b.h[1];
#endif
}

// ---------------- dtype sniff ----------------
__global__ void sniff_kernel(const unsigned short* __restrict__ w, int* __restrict__ flag){
  __shared__ int cnt;
  if (threadIdx.x == 0) cnt = 0;
  __syncthreads();
  int ok = 0;
  for (int i = threadIdx.x; i < 2048; i += 256){
    float a = fabsf(b2f(w[2 * i]));
    if (a > 1e-8f && a < 4.f) ok++;
  }
  atomicAdd(&cnt, ok);
  __syncthreads();
  if (threadIdx.x == 0) *flag = (cnt >= 1024) ? 1 : 0;
}

// ---------------- convert all float weights into one fp32 buffer ----------------
struct CvtArgs {
  const void* src[24];
  int off[25];
};
__global__ void cvtw_kernel(CvtArgs a, const int* __restrict__ flag, float* __restrict__ W){
  int t = blockIdx.x * blockDim.x + threadIdx.x;
  if (t >= WTOTAL) return;
  int k = 0;
  while (t >= a.off[k + 1]) ++k;
  int rel = t - a.off[k];
  float v;
  if (*flag) v = b2f(((const unsigned short*)a.src[k])[rel]);
  else       v = ((const float*)a.src[k])[rel];
  W[t] = v;
}

// ---------------- convert x -> bf16 ----------------
__global__ void cvtx_kernel(const void* __restrict__ x, const int* __restrict__ flag,
                            unsigned short* __restrict__ P){
  int i = blockIdx.x * blockDim.x + threadIdx.x;
  if (*flag) P[i] = ((const unsigned short*)x)[i];
  else       P[i] = f2b(((const float*)x)[i]);
}

// ---------------- pack B matrices to bf16 (Wih transposed to [K][N]) ----------------
__global__ void packb_kernel(const float* __restrict__ Wbuf, unsigned short* __restrict__ BBF){
  int id = blockIdx.x * blockDim.x + threadIdx.x;
  if (id >= BTOTAL) return;
  float v;
  if (id < BOFF_G1)       v = Wbuf[WOFF_G0W + id];
  else if (id < BOFF_G2)  v = Wbuf[WOFF_G1W + (id - BOFF_G1)];
  else if (id < BOFF_WF)  v = Wbuf[WOFF_G2W + (id - BOFF_G2)];
  else if (id < BOFF_WB){ int r = id - BOFF_WF; int k = r >> 10, n = r & 1023;
                          v = Wbuf[WOFF_WIHF + n * 64 + k]; }
  else                  { int r = id - BOFF_WB; int k = r >> 10, n = r & 1023;
                          v = Wbuf[WOFF_WIHB + n * 64 + k]; }
  BBF[id] = f2b(v);
}

// ---------------- CSR build ----------------
__global__ void csr_kernel(const int* __restrict__ ei, int* __restrict__ row,
                           int* __restrict__ colsrc, int* __restrict__ coldst){
  __shared__ int cnt[NNODE];
  __shared__ int off[NNODE];
  int tid = threadIdx.x;
  for (int i = tid; i < NNODE; i += blockDim.x) cnt[i] = 0;
  __syncthreads();
  for (int i = tid; i < ESLOTS; i += blockDim.x){
    int d = (i < EPG) ? ei[EPG + i] : (i - EPG);
    atomicAdd(&cnt[d], 1);
  }
  __syncthreads();
  if (tid == 0){
    int acc = 0;
    for (int i = 0; i < NNODE; ++i){ row[i] = acc; off[i] = acc; acc += cnt[i]; }
    row[NNODE] = acc;
  }
  __syncthreads();
  for (int i = tid; i < ESLOTS; i += blockDim.x){
    int s, d;
    if (i < EPG){ s = ei[i]; d = ei[EPG + i]; } else { s = i - EPG; d = i - EPG; }
    int pos = atomicAdd(&off[d], 1);
    colsrc[pos] = s; coldst[pos] = d;
  }
}

// ---------------- MFMA matmul: C[M,Nc] = A[M,K](bf16) @ B[K,Nc](bf16) ----------------
// 64x64 tile per block, 4 waves, 16x16x32 MFMA. K multiple of 16 (zero-padded to 32-chunks).
template<int CBF16>
__global__ __launch_bounds__(256)
void mmx_kernel(const unsigned short* __restrict__ A, const unsigned short* __restrict__ Bb,
                void* __restrict__ Cv, int M, int Nc, int K)
{
  __shared__ unsigned short As[64][40];   // row-major [m][k], stride 40 u16 (80B)
  __shared__ unsigned short Bs[64][40];   // transposed [n][k]
  const int tid = threadIdx.x;
  const int w = tid >> 6, lane = tid & 63, q = lane >> 4, r = lane & 15;
  const int m0 = blockIdx.x * 64, n0 = blockIdx.y * 64;
  float4v acc0 = {0,0,0,0}, acc1 = {0,0,0,0}, acc2 = {0,0,0,0}, acc3 = {0,0,0,0};
  const int arow = tid >> 2, akb = (tid & 3) * 8;
  const int bk = tid >> 3, bnb = (tid & 7) * 8;
  for (int kc = 0; kc < K; kc += 32){
    int kw = K - kc; if (kw > 32) kw = 32;
    if (akb < kw){
      uint4 v = *(const uint4*)(A + (size_t)(m0 + arow) * K + kc + akb);
      *(uint4*)&As[arow][akb] = v;
    } else {
      uint4 z = {0,0,0,0}; *(uint4*)&As[arow][akb] = z;
    }
    if (bk < kw){
      uint4 v = *(const uint4*)(Bb + (size_t)(kc + bk) * Nc + n0 + bnb);
      const unsigned short* vs = (const unsigned short*)&v;
      #pragma unroll
      for (int e = 0; e < 8; ++e) Bs[bnb + e][bk] = vs[e];
    } else {
      #pragma unroll
      for (int e = 0; e < 8; ++e) Bs[bnb + e][bk] = 0;
    }
    __syncthreads();
    short8 af = *(const short8*)&As[16 * w + r][q * 8];
    short8 b0 = *(const short8*)&Bs[r][q * 8];
    short8 b1 = *(const short8*)&Bs[16 + r][q * 8];
    short8 b2 = *(const short8*)&Bs[32 + r][q * 8];
    short8 b3 = *(const short8*)&Bs[48 + r][q * 8];
    acc0 = __builtin_amdgcn_mfma_f32_16x16x32_bf16(af, b0, acc0, 0, 0, 0);
    acc1 = __builtin_amdgcn_mfma_f32_16x16x32_bf16(af, b1, acc1, 0, 0, 0);
    acc2 = __builtin_amdgcn_mfma_f32_16x16x32_bf16(af, b2, acc2, 0, 0, 0);
    acc3 = __builtin_amdgcn_mfma_f32_16x16x32_bf16(af, b3, acc3, 0, 0, 0);
    __syncthreads();
  }
  const int row = m0 + 16 * w + q * 4, col0 = n0 + r;
  if (CBF16){
    unsigned short* C = (unsigned short*)Cv;
    #pragma unroll
    for (int i = 0; i < 4; ++i){
      size_t base = (size_t)(row + i) * Nc;
      C[base + col0]      = f2b(acc0[i]);
      C[base + col0 + 16] = f2b(acc1[i]);
      C[base + col0 + 32] = f2b(acc2[i]);
      C[base + col0 + 48] = f2b(acc3[i]);
    }
  } else {
    float* C = (float*)Cv;
    #pragma unroll
    for (int i = 0; i < 4; ++i){
      size_t base = (size_t)(row + i) * Nc;
      C[base + col0]      = acc0[i];
      C[base + col0 + 16] = acc1[i];
      C[base + col0 + 32] = acc2[i];
      C[base + col0 + 48] = acc3[i];
    }
  }
}

// ---------------- attention logits per (node, head) ----------------
__global__ void al_kernel(const unsigned short* __restrict__ H, const float* __restrict__ asrc,
                          const float* __restrict__ adst,
                          float* __restrict__ ALS, float* __restrict__ ALD, int HD, int Hh)
{
  int n = blockIdx.x;
  int tid = threadIdx.x;
  float hv = b2f(H[(size_t)n * HD + tid]);
  float vs = hv * asrc[tid];
  float vd = hv * adst[tid];
  #pragma unroll
  for (int m = 32; m >= 1; m >>= 1){ vs += __shfl_xor(vs, m); vd += __shfl_xor(vd, m); }
  if ((tid & 63) == 0){
    int h = tid >> 6;
    ALS[(size_t)n * Hh + h] = vs;
    ALD[(size_t)n * Hh + h] = vd;
  }
}

// ---------------- fused softmax+aggregate+bias+relu: block = dst node ----------------
__global__ void fagg_kernel(const unsigned short* __restrict__ H,
                            const float* __restrict__ ALS, const float* __restrict__ ALD,
                            const int* __restrict__ row, const int* __restrict__ colsrc,
                            const float* __restrict__ bias,
                            unsigned short* __restrict__ O, int HD, int Hh)
{
  int n = blockIdx.x, tid = threadIdx.x;
  int g = n >> 7, dn = n & 127;
  int h = tid >> 6, lane = tid & 63;
  int rs = row[dn], re = row[dn + 1];
  float aldv = ALD[(size_t)n * Hh + h];
  const float* ALSg = ALS + (size_t)g * NNODE * Hh;

  float mx = -3e38f, den = 0.f;
  for (int base = rs; base < re; base += 64){
    int e = base + lane;
    float v = -3e38f;
    if (e < re){
      int s = colsrc[e];
      float t = ALSg[s * Hh + h] + aldv;
      v = t > 0.f ? t : 0.2f * t;
    }
    float mp = v;
    #pragma unroll
    for (int m = 32; m >= 1; m >>= 1) mp = fmaxf(mp, __shfl_xor(mp, m));
    float dp = (e < re) ? __expf(v - mp) : 0.f;
    #pragma unroll
    for (int m = 32; m >= 1; m >>= 1) dp += __shfl_xor(dp, m);
    if (mp > mx){ den = den * __expf(mx - mp) + dp; mx = mp; }
    else den += dp * __expf(mp - mx);
  }
  float iden = 1.f / (den + 1e-16f);

  const unsigned short* Hg = H + (size_t)g * NNODE * HD;
  float acc = 0.f;
  for (int e = rs; e < re; ++e){
    int s = colsrc[e];
    float t = ALSg[s * Hh + h] + aldv;
    t = t > 0.f ? t : 0.2f * t;
    float w = __expf(t - mx) * iden;
    acc += w * b2f(Hg[(size_t)s * HD + tid]);
  }
  float o = acc + bias[tid];
  O[(size_t)n * HD + tid] = f2b(o > 0.f ? o : 0.f);
}

// ---------------- graph sum-pool -> seq layout [t][b][HIDD] (bf16) ----------------
__global__ void pool_kernel(const unsigned short* __restrict__ X3, unsigned short* __restrict__ XSEQ){
  int id = blockIdx.x * blockDim.x + threadIdx.x;
  if (id >= NGRAPH * HIDD) return;
  int g = id >> 6, f = id & 63;
  const unsigned short* p = X3 + (size_t)g * NNODE * HIDD + f;
  float s = 0.f;
  for (int dn = 0; dn < NNODE; ++dn) s += b2f(p[dn * HIDD]);
  int b = g >> 6, t = g & 63;
  XSEQ[(size_t)(t * BSZ + b) * HIDD + f] = f2b(s);
}

// ---------------- pack Whh into f16-pair, interleaved: WT[d][kk4][u][c] ----------------
__global__ void packwhh_kernel(const float* __restrict__ Wbuf, unsigned int* __restrict__ WT){
  int id = blockIdx.x * blockDim.x + threadIdx.x;   // < 262144
  int d = id >> 17;
  int r = id & 131071;
  int c = r & 3;
  int u = (r >> 2) & 1023;
  int kk4 = r >> 12;
  int kk = kk4 * 4 + c;
  const float* W = Wbuf + (d ? WOFF_WHHB : WOFF_WHHF);
  _Float16 a = (_Float16)W[u * RHID + 2 * kk];
  _Float16 b = (_Float16)W[u * RHID + 2 * kk + 1];
  union { _Float16 h; unsigned short s; } ua, ub; ua.h = a; ub.h = b;
  WT[id] = (unsigned int)ua.s | ((unsigned int)ub.s << 16);
}

// ---------------- LSTM, M-split, shfl-pack publish + per-peer eager fetch ----------------
// 8 WGs = 2 dirs x 4 unit-slices; 256 threads; 128 KB LDS weights.
// FLG[dir][t][m] one-shot flags (memset 0). HX double-buffered by t&1.
__global__ __launch_bounds__(256)
void lstm6_kernel(const float* __restrict__ XF, const float* __restrict__ XB,
                  const unsigned int* __restrict__ WT,
                  const float* __restrict__ bih_f, const float* __restrict__ bhh_f,
                  const float* __restrict__ bih_b, const float* __restrict__ bhh_b,
                  int* __restrict__ FLG, unsigned int* __restrict__ HX,
                  float* __restrict__ HT)
{
  __shared__ unsigned int WL[32][256][4];     // 128 KB weight slice
  __shared__ unsigned int h2u[512];           // full h, f16 pairs, [b][128]
  __shared__ float glds[4][64][5];            // [gate][unit][batch], padded

  const int tid = threadIdx.x;
  const int m = blockIdx.x & 3, dir = blockIdx.x >> 2;
  const int gq = tid >> 6, jl = tid & 63;
  const int u = gq * 256 + 64 * m + jl;
  const float* Xp = dir ? XB : XF;
  const float bias = (dir ? bih_b : bih_f)[u] + (dir ? bhh_b : bhh_f)[u];
  const int ub = tid >> 6, uj = tid & 63;
  int* FLGd = FLG + dir * 256;
  unsigned int* HXd = HX + dir * 1024;

  {
    const uint4* WT4 = (const uint4*)(WT + (dir << 17));
    #pragma unroll
    for (int kk4 = 0; kk4 < 32; ++kk4)
      *(uint4*)WL[kk4][tid] = WT4[(kk4 << 10) + u];
  }
  for (int i = tid; i < 512; i += 256) h2u[i] = 0;
  float c = 0.f;
  __syncthreads();

  for (int t = 0; t < TT; ++t){
    const int tb = dir ? (TT - 1 - t) : t;
    const float* xr = Xp + (size_t)(tb * 4) * 1024 + u;
    float a0 = bias + xr[0];
    float a1 = bias + xr[1024];
    float a2 = bias + xr[2048];
    float a3 = bias + xr[3072];
    #pragma unroll 4
    for (int kk4 = 0; kk4 < 32; ++kk4){
      uint4 w4 = *(const uint4*)WL[kk4][tid];
      uint4 hb0 = *(const uint4*)&h2u[0 * 128 + (kk4 << 2)];
      uint4 hb1 = *(const uint4*)&h2u[1 * 128 + (kk4 << 2)];
      uint4 hb2 = *(const uint4*)&h2u[2 * 128 + (kk4 << 2)];
      uint4 hb3 = *(const uint4*)&h2u[3 * 128 + (kk4 << 2)];
      a0 = dot2h(w4.x, hb0.x, a0); a0 = dot2h(w4.y, hb0.y, a0);
      a0 = dot2h(w4.z, hb0.z, a0); a0 = dot2h(w4.w, hb0.w, a0);
      a1 = dot2h(w4.x, hb1.x, a1); a1 = dot2h(w4.y, hb1.y, a1);
      a1 = dot2h(w4.z, hb1.z, a1); a1 = dot2h(w4.w, hb1.w, a1);
      a2 = dot2h(w4.x, hb2.x, a2); a2 = dot2h(w4.y, hb2.y, a2);
      a2 = dot2h(w4.z, hb2.z, a2); a2 = dot2h(w4.w, hb2.w, a2);
      a3 = dot2h(w4.x, hb3.x, a3); a3 = dot2h(w4.y, hb3.y, a3);
      a3 = dot2h(w4.z, hb3.z, a3); a3 = dot2h(w4.w, hb3.w, a3);
    }
    glds[gq][jl][0] = a0; glds[gq][jl][1] = a1;
    glds[gq][jl][2] = a2; glds[gq][jl][3] = a3;
    __syncthreads();

    // updater: thread (ub,uj) owns (batch, unit)
    float gi = glds[0][uj][ub];
    float gf = glds[1][uj][ub];
    float gg = glds[2][uj][ub];
    float go = glds[3][uj][ub];
    float si = 1.f / (1.f + __expf(-gi));
    float sf = 1.f / (1.f + __expf(-gf));
    float so = 1.f / (1.f + __expf(-go));
    float tg = 1.f - 2.f / (1.f + __expf(2.f * gg));
    c = sf * c + si * tg;
    float ch = 1.f - 2.f / (1.f + __expf(2.f * c));
    float hval = so * ch;
    if (t == TT - 1){
      HT[(size_t)(dir * 4 + ub) * RHID + (64 * m + uj)] = hval;
      break;
    }
    // pack pair via shfl, even lanes publish
    union { _Float16 h; unsigned short s; } uh; uh.h = (_Float16)hval;
    unsigned int own = uh.s;
    unsigned int partner = ((unsigned int)__shfl_xor((int)own, 1)) & 0xffffu;
    unsigned int* HXs = HXd + (t & 1) * 512;
    if ((uj & 1) == 0){
      unsigned int v = own | (partner << 16);
      int p = uj >> 1;
      h2u[ub * 128 + 32 * m + p] = v;
      __hip_atomic_store(&HXs[ub * 128 + 32 * m + p], v,
                         __ATOMIC_RELAXED, __HIP_MEMORY_SCOPE_AGENT);
    }
    __syncthreads();                 // drains publish stores (vmcnt) before flag
    if (tid == 0)
      __hip_atomic_store(&FLGd[t * 4 + m], 1, __ATOMIC_RELEASE, __HIP_MEMORY_SCOPE_AGENT);
    if (gq > 0){                     // wave gq fetches peer (m+gq)&3
      int qp = (m + gq) & 3;
      if (jl == 0){
        int guard = 0;
        while (__hip_atomic_load(&FLGd[t * 4 + qp], __ATOMIC_ACQUIRE,
                                 __HIP_MEMORY_SCOPE_AGENT) == 0 && guard < 100000000){
          __builtin_amdgcn_s_sleep(1);
          ++guard;
        }
      }
      int b2 = jl >> 5, p2 = jl & 31;
      h2u[b2 * 128 + 32 * qp + p2] =
        __hip_atomic_load(&HXs[b2 * 128 + 32 * qp + p2],
                          __ATOMIC_RELAXED, __HIP_MEMORY_SCOPE_AGENT);
      h2u[(b2 + 2) * 128 + 32 * qp + p2] =
        __hip_atomic_load(&HXs[(b2 + 2) * 128 + 32 * qp + p2],
                          __ATOMIC_RELAXED, __HIP_MEMORY_SCOPE_AGENT);
    }
    __syncthreads();
  }
}

// ---------------- heads + Poincare projection, fp32 out (coalesced) ----------------
__global__ __launch_bounds__(512)
void head2_kernel(const float* __restrict__ HT,
                  const float* __restrict__ muW, const float* __restrict__ mub,
                  const float* __restrict__ lvW, const float* __restrict__ lvb,
                  float* __restrict__ out)
{
  __shared__ float feat[4][512];
  __shared__ float muv[4][64];
  __shared__ float lvv[4][64];
  int tid = threadIdx.x;
  for (int i = tid; i < 2048; i += 512){
    int rr = i >> 8, k = i & 255;
    int b = rr & 3, d = rr >> 2;
    feat[b][d * 256 + k] = HT[i];
  }
  __syncthreads();
  int w = tid >> 6, lane = tid & 63;
  for (int job = w; job < 512; job += 8){
    int j = job & 63, b = (job >> 6) & 3, mat = job >> 8;
    const float* W = (mat ? lvW : muW) + (size_t)j * 512;
    float s = 0.f;
    #pragma unroll
    for (int e = 0; e < 8; ++e) s += W[lane * 8 + e] * feat[b][lane * 8 + e];
    #pragma unroll
    for (int mm = 32; mm >= 1; mm >>= 1) s += __shfl_xor(s, mm);
    if (lane == 0){
      float v = s + (mat ? lvb[j] : mub[j]);
      if (mat) lvv[b][j] = v; else muv[b][j] = v;
    }
  }
  __syncthreads();
  if (tid < 256){
    int b = tid >> 6, j = tid & 63;
    float mu = muv[b][j];
    float sq = mu * mu;
    #pragma unroll
    for (int mm = 32; mm >= 1; mm >>= 1) sq += __shfl_xor(sq, mm);
    float nrm = sqrtf(sq);
    const float mxn = 1.0f - 4e-3f;
    if (nrm > mxn) mu = mu / nrm * mxn;
    out[b * 64 + j] = mu;
    out[256 + b * 64 + j] = lvv[b][j];
  }
}

extern "C" void kernel_launch(void* const* d_in, const int* in_sizes, int n_in,
                              void* d_out, int out_size, void* d_ws, size_t ws_size,
                              hipStream_t stream)
{
  const int* ei = (const int*)d_in[1];

  int*   ws_i    = (int*)d_ws;
  int*   dflag   = ws_i;
  int*   csr_row = ws_i + 256;
  int*   csr_src = ws_i + 512;
  int*   csr_dst = ws_i + 2048;
  float* FW   = (float*)d_ws;
  float* Wbuf = FW + FOFF_WBUF;
  float* ALS  = FW + FOFF_ALS;
  float* ALD  = FW + FOFF_ALD;
  float* XFp  = FW + FOFF_XFP;
  float* XBp  = FW + FOFF_XBP;
  float* HT   = FW + FOFF_HT;
  unsigned short* XSEQ = (unsigned short*)(FW + FOFF_XSEQ);
  unsigned short* Hb   = (unsigned short*)(FW + FOFF_H);
  unsigned short* Pb   = (unsigned short*)(FW + FOFF_P);
  unsigned int*   WT   = (unsigned int*)(FW + FOFF_WE);
  unsigned short* BBF  = (unsigned short*)(FW + FOFF_BBF);
  int*            FLG  = (int*)(FW + FOFF_SYNC);                 // 512 ints
  unsigned int*   HX   = (unsigned int*)(FW + FOFF_SYNC + 512);  // 2048 uints

  // ---- dtype sniff + canonicalize inputs ----
  sniff_kernel<<<1, 256, 0, stream>>>((const unsigned short*)d_in[2], dflag);

  CvtArgs ca;
  static const int wsz[24] = {4096,256,256,256, 65536,256,256,256, 16384,64,64,64,
                              65536,262144,1024,1024, 65536,262144,1024,1024,
                              32768,64,32768,64};
  {
    int acc = 0;
    for (int k = 0; k < 24; ++k){ ca.src[k] = d_in[2 + k]; ca.off[k] = acc; acc += wsz[k]; }
    ca.off[24] = acc;
  }
  cvtw_kernel<<<(WTOTAL + 255) / 256, 256, 0, stream>>>(ca, dflag, Wbuf);
  packb_kernel<<<(BTOTAL + 255) / 256, 256, 0, stream>>>(Wbuf, BBF);
  cvtx_kernel<<<(NTOT * NFEAT) / 256, 256, 0, stream>>>(d_in[0], dflag, Pb);
  csr_kernel<<<1, 256, 0, stream>>>(ei, csr_row, csr_src, csr_dst);

  // ---- GAT layer 0 ----
  mmx_kernel<1><<<dim3(512, 4), 256, 0, stream>>>(Pb, BBF + BOFF_G0, Hb, NTOT, 256, 16);
  al_kernel<<<NTOT, 256, 0, stream>>>(Hb, Wbuf + WOFF_G0AS, Wbuf + WOFF_G0AD, ALS, ALD, 256, 4);
  fagg_kernel<<<NTOT, 256, 0, stream>>>(Hb, ALS, ALD, csr_row, csr_src, Wbuf + WOFF_G0B, Pb, 256, 4);

  // ---- GAT layer 1 ----
  mmx_kernel<1><<<dim3(512, 4), 256, 0, stream>>>(Pb, BBF + BOFF_G1, Hb, NTOT, 256, 256);
  al_kernel<<<NTOT, 256, 0, stream>>>(Hb, Wbuf + WOFF_G1AS, Wbuf + WOFF_G1AD, ALS, ALD, 256, 4);
  fagg_kernel<<<NTOT, 256, 0, stream>>>(Hb, ALS, ALD, csr_row, csr_src, Wbuf + WOFF_G1B, Pb, 256, 4);

  // ---- GAT layer 2 (1 head) ----
  mmx_kernel<1><<<dim3(512, 1), 256, 0, stream>>>(Pb, BBF + BOFF_G2, Hb, NTOT, 64, 256);
  al_kernel<<<NTOT, 64, 0, stream>>>(Hb, Wbuf + WOFF_G2AS, Wbuf + WOFF_G2AD, ALS, ALD, 64, 1);
  fagg_kernel<<<NTOT, 64, 0, stream>>>(Hb, ALS, ALD, csr_row, csr_src, Wbuf + WOFF_G2B, Pb, 64, 1);

  // ---- pool + LSTM input precompute ----
  pool_kernel<<<(NGRAPH * HIDD) / 256, 256, 0, stream>>>(Pb, XSEQ);
  mmx_kernel<0><<<dim3(4, 16), 256, 0, stream>>>(XSEQ, BBF + BOFF_WF, XFp, 256, 1024, 64);
  mmx_kernel<0><<<dim3(4, 16), 256, 0, stream>>>(XSEQ, BBF + BOFF_WB, XBp, 256, 1024, 64);

  // ---- pack + LSTM (8 WGs, flag region zeroed first — capture-legal) ----
  packwhh_kernel<<<1024, 256, 0, stream>>>(Wbuf, WT);
  hipMemsetAsync((void*)FLG, 0, 2048, stream);
  lstm6_kernel<<<8, 256, 0, stream>>>(XFp, XBp, WT,
                                      Wbuf + WOFF_BIHF, Wbuf + WOFF_BHHF,
                                      Wbuf + WOFF_BIHB, Wbuf + WOFF_BHHB,
                                      FLG, HX, HT);

  // ---- heads + projection ----
  head2_kernel<<<1, 512, 0, stream>>>(HT, Wbuf + WOFF_MUW, Wbuf + WOFF_MUB,
                                      Wbuf + WOFF_LVW, Wbuf + WOFF_LVB, (float*)d_out);
}

// Round 8
// 644.772 us; speedup vs baseline: 3.6304x; 1.2057x over previous
//
#include <hip/hip_runtime.h>
#include <hip/hip_bf16.h>

// ---- problem constants ----
#define BSZ 4
#define TT 64
#define NNODE 128
#define NFEAT 16
#define HIDD 64
#define NHEAD 4
#define RHID 256
#define LDIM 64
#define EPG 1024
#define NGRAPH (BSZ*TT)          // 256
#define NTOT (NGRAPH*NNODE)      // 32768
#define ESLOTS (EPG+NNODE)       // 1152

// ---- canonical fp32 weight buffer offsets (floats) ----
#define WOFF_G0W 0
#define WOFF_G0AS 4096
#define WOFF_G0AD 4352
#define WOFF_G0B 4608
#define WOFF_G1W 4864
#define WOFF_G1AS 70400
#define WOFF_G1AD 70656
#define WOFF_G1B 70912
#define WOFF_G2W 71168
#define WOFF_G2AS 87552
#define WOFF_G2AD 87616
#define WOFF_G2B 87680
#define WOFF_WIHF 87744
#define WOFF_WHHF 153280
#define WOFF_BIHF 415424
#define WOFF_BHHF 416448
#define WOFF_WIHB 417472
#define WOFF_WHHB 483008
#define WOFF_BIHB 745152
#define WOFF_BHHB 746176
#define WOFF_MUW 747200
#define WOFF_MUB 779968
#define WOFF_LVW 780032
#define WOFF_LVB 812800
#define WTOTAL   812864

// ---- workspace float offsets ----
#define FOFF_WBUF 4096
#define FOFF_SYNC 1314816      // FLG (512 ints) + HX (2048 uints)
#define FOFF_WE   1576960      // WT lives here
#define FOFF_BBF  1900000      // bf16 B matrices (u16 view)
#define FOFF_XFP  2756608
#define FOFF_XBP  3018752
#define FOFF_HT   3280896
#define FOFF_XSEQ 3282944
#define FOFF_P    7485440

// bf16 B-matrix u16 offsets inside BBF
#define BOFF_G0 0
#define BOFF_G1 4096
#define BOFF_G2 69632
#define BOFF_WF 86016
#define BOFF_WB 151552
#define BTOTAL  217088

typedef __attribute__((ext_vector_type(8))) short short8;
typedef __attribute__((ext_vector_type(4))) float float4v;

__device__ __forceinline__ float b2f(unsigned short u){
  union { unsigned int i; float f; } v; v.i = ((unsigned int)u) << 16; return v.f;
}
__device__ __forceinline__ unsigned short f2b(float f){
  __hip_bfloat16 h = __float2bfloat16(f);
  union { __hip_bfloat16 h; unsigned short u; } v; v.h = h; return v.u;
}

// fused half2 dot: acc += w.x*h.x + w.y*h.y
__device__ __forceinline__ float dot2h(unsigned int w, unsigned int h, float acc){
#if __has_builtin(__builtin_amdgcn_fdot2)
  typedef _Float16 h2v __attribute__((ext_vector_type(2)));
  union { unsigned int u; h2v v; } a, b; a.u = w; b.u = h;
  return __builtin_amdgcn_fdot2(a.v, b.v, acc, false);
#else
  union { unsigned int u; _Float16 h[2]; } a, b; a.u = w; b.u = h;
  return acc + (float)a.h[0] * (float)b.h[0] + (float)a.h[1] * (float)b.h[1];
#endif
}

// ---------------- dtype sniff ----------------
__global__ void sniff_kernel(const unsigned short* __restrict__ w, int* __restrict__ flag){
  __shared__ int cnt;
  if (threadIdx.x == 0) cnt = 0;
  __syncthreads();
  int ok = 0;
  for (int i = threadIdx.x; i < 2048; i += 256){
    float a = fabsf(b2f(w[2 * i]));
    if (a > 1e-8f && a < 4.f) ok++;
  }
  atomicAdd(&cnt, ok);
  __syncthreads();
  if (threadIdx.x == 0) *flag = (cnt >= 1024) ? 1 : 0;
}

// ---------------- convert all float weights into one fp32 buffer ----------------
struct CvtArgs {
  const void* src[24];
  int off[25];
};
__global__ void cvtw_kernel(CvtArgs a, const int* __restrict__ flag, float* __restrict__ W){
  int t = blockIdx.x * blockDim.x + threadIdx.x;
  if (t >= WTOTAL) return;
  int k = 0;
  while (t >= a.off[k + 1]) ++k;
  int rel = t - a.off[k];
  float v;
  if (*flag) v = b2f(((const unsigned short*)a.src[k])[rel]);
  else       v = ((const float*)a.src[k])[rel];
  W[t] = v;
}

// ---------------- convert x -> bf16 ----------------
__global__ void cvtx_kernel(const void* __restrict__ x, const int* __restrict__ flag,
                            unsigned short* __restrict__ P){
  int i = blockIdx.x * blockDim.x + threadIdx.x;
  if (*flag) P[i] = ((const unsigned short*)x)[i];
  else       P[i] = f2b(((const float*)x)[i]);
}

// ---------------- pack B matrices to bf16 (Wih transposed to [K][N]) ----------------
__global__ void packb_kernel(const float* __restrict__ Wbuf, unsigned short* __restrict__ BBF){
  int id = blockIdx.x * blockDim.x + threadIdx.x;
  if (id >= BTOTAL) return;
  float v;
  if (id < BOFF_G1)       v = Wbuf[WOFF_G0W + id];
  else if (id < BOFF_G2)  v = Wbuf[WOFF_G1W + (id - BOFF_G1)];
  else if (id < BOFF_WF)  v = Wbuf[WOFF_G2W + (id - BOFF_G2)];
  else if (id < BOFF_WB){ int r = id - BOFF_WF; int k = r >> 10, n = r & 1023;
                          v = Wbuf[WOFF_WIHF + n * 64 + k]; }
  else                  { int r = id - BOFF_WB; int k = r >> 10, n = r & 1023;
                          v = Wbuf[WOFF_WIHB + n * 64 + k]; }
  BBF[id] = f2b(v);
}

// ---------------- CSR build ----------------
__global__ void csr_kernel(const int* __restrict__ ei, int* __restrict__ row,
                           int* __restrict__ colsrc, int* __restrict__ coldst){
  __shared__ int cnt[NNODE];
  __shared__ int off[NNODE];
  int tid = threadIdx.x;
  for (int i = tid; i < NNODE; i += blockDim.x) cnt[i] = 0;
  __syncthreads();
  for (int i = tid; i < ESLOTS; i += blockDim.x){
    int d = (i < EPG) ? ei[EPG + i] : (i - EPG);
    atomicAdd(&cnt[d], 1);
  }
  __syncthreads();
  if (tid == 0){
    int acc = 0;
    for (int i = 0; i < NNODE; ++i){ row[i] = acc; off[i] = acc; acc += cnt[i]; }
    row[NNODE] = acc;
  }
  __syncthreads();
  for (int i = tid; i < ESLOTS; i += blockDim.x){
    int s, d;
    if (i < EPG){ s = ei[i]; d = ei[EPG + i]; } else { s = i - EPG; d = i - EPG; }
    int pos = atomicAdd(&off[d], 1);
    colsrc[pos] = s; coldst[pos] = d;
  }
}

// ---------------- fused 3-layer GAT + pool: one block per graph ----------------
// LDS: HA/HB h-buffers (rows padded to 264 u16), Bst B-chunk, AW edge weights.
__global__ __launch_bounds__(256, 1)
void gatall_kernel(const unsigned short* __restrict__ X,
                   const unsigned short* __restrict__ BBF,
                   const float* __restrict__ Wbuf,
                   const int* __restrict__ csr_row, const int* __restrict__ csr_src,
                   unsigned short* __restrict__ XSEQ)
{
  __shared__ unsigned short HAs[128 * 264];   // 67584 B
  __shared__ unsigned short HBs[128 * 264];   // 67584 B
  __shared__ unsigned short Bst[128 * 40];    // 10240 B
  __shared__ unsigned short AWs[1152 * 4];    //  9216 B
  __shared__ float ALSs[512];                 //  2048 B
  __shared__ float ALDs[512];                 //  2048 B
  __shared__ int   rowL[132];                 //   528 B
  __shared__ unsigned short srcL[1152];       //  2304 B

  const int tid = threadIdx.x;
  const int g = blockIdx.x;
  const int w = tid >> 6, lane = tid & 63, q = lane >> 4, r = lane & 15;

  for (int i = tid; i < 129; i += 256) rowL[i] = csr_row[i];
  for (int i = tid; i < 1152; i += 256) srcL[i] = (unsigned short)csr_src[i];

  float4v acc0[16], acc1[16];

  //======== Layer 0 GEMM: h0[128,256] = X[g] @ g0W (K=16, zero-padded) ========
  #pragma unroll
  for (int i = 0; i < 16; ++i){ acc0[i] = (float4v){0,0,0,0}; acc1[i] = (float4v){0,0,0,0}; }
  short8 xa0 = {0,0,0,0,0,0,0,0}, xa1 = {0,0,0,0,0,0,0,0};
  if (q < 2){
    xa0 = *(const short8*)(X + ((size_t)(g * 128 + 16 * w       + r)) * 16 + q * 8);
    xa1 = *(const short8*)(X + ((size_t)(g * 128 + 16 * (w + 4) + r)) * 16 + q * 8);
  }
  for (int nh = 0; nh < 2; ++nh){
    __syncthreads();
    #pragma unroll
    for (int p = 0; p < 2; ++p){
      int k2 = tid >> 3, c = (tid & 7) * 8;
      uint4 v = {0,0,0,0};
      if (k2 < 16) v = *(const uint4*)(BBF + BOFF_G0 + (size_t)k2 * 256 + nh * 128 + p * 64 + c);
      const unsigned short* vs = (const unsigned short*)&v;
      #pragma unroll
      for (int e = 0; e < 8; ++e) Bst[(p * 64 + c + e) * 40 + k2] = vs[e];
    }
    __syncthreads();
    #pragma unroll
    for (int nt = 0; nt < 8; ++nt){
      short8 bf = *(const short8*)&Bst[(16 * nt + r) * 40 + q * 8];
      acc0[nh * 8 + nt] = __builtin_amdgcn_mfma_f32_16x16x32_bf16(xa0, bf, acc0[nh * 8 + nt], 0, 0, 0);
      acc1[nh * 8 + nt] = __builtin_amdgcn_mfma_f32_16x16x32_bf16(xa1, bf, acc1[nh * 8 + nt], 0, 0, 0);
    }
  }
  __syncthreads();
  #pragma unroll
  for (int nt = 0; nt < 16; ++nt)
    #pragma unroll
    for (int i = 0; i < 4; ++i){
      HAs[(16 * w       + q * 4 + i) * 264 + 16 * nt + r] = f2b(acc0[nt][i]);
      HAs[(16 * (w + 4) + q * 4 + i) * 264 + 16 * nt + r] = f2b(acc1[nt][i]);
    }
  __syncthreads();

  //======== macro-ish helpers via lambdas for attention/agg (HD=256, Hh=4) ========
  auto attn256 = [&](int asoff, int adoff){
    float4 as4 = *(const float4*)(Wbuf + asoff + 4 * lane);
    float4 ad4 = *(const float4*)(Wbuf + adoff + 4 * lane);
    for (int it = 0; it < 32; ++it){
      int n = it * 4 + w;
      const unsigned short* hp = &HAs[n * 264 + 4 * lane];
      float e0 = b2f(hp[0]), e1 = b2f(hp[1]), e2 = b2f(hp[2]), e3 = b2f(hp[3]);
      float vs = e0 * as4.x + e1 * as4.y + e2 * as4.z + e3 * as4.w;
      float vd = e0 * ad4.x + e1 * ad4.y + e2 * ad4.z + e3 * ad4.w;
      #pragma unroll
      for (int m = 8; m >= 1; m >>= 1){ vs += __shfl_xor(vs, m); vd += __shfl_xor(vd, m); }
      if ((lane & 15) == 0){ ALSs[n * 4 + (lane >> 4)] = vs; ALDs[n * 4 + (lane >> 4)] = vd; }
    }
    __syncthreads();
    // per-(dst,head) softmax weights -> AWs (f16)
    for (int pass = 0; pass < 2; ++pass){
      int jid = pass * 256 + tid;
      int n = jid >> 2, h = jid & 3;
      float aldv = ALDs[n * 4 + h];
      int rs = rowL[n], re = rowL[n + 1];
      float mx = -3e38f, den = 0.f;
      for (int j = rs; j < re; ++j){
        float v = ALSs[srcL[j] * 4 + h] + aldv;
        v = v > 0.f ? v : 0.2f * v;
        if (v > mx){ den = den * __expf(mx - v) + 1.f; mx = v; }
        else den += __expf(v - mx);
      }
      float iden = 1.f / (den + 1e-16f);
      for (int j = rs; j < re; ++j){
        float v = ALSs[srcL[j] * 4 + h] + aldv;
        v = v > 0.f ? v : 0.2f * v;
        union { _Float16 hh; unsigned short s; } uu;
        uu.hh = (_Float16)(__expf(v - mx) * iden);
        AWs[j * 4 + h] = uu.s;
      }
    }
    __syncthreads();
  };
  auto agg256 = [&](int boff){
    int f4 = (lane) * 4;
    int h = lane >> 4;
    float4 bz = *(const float4*)(Wbuf + boff + f4);
    for (int n = w; n < 128; n += 4){
      int rs = rowL[n], re = rowL[n + 1];
      float A0 = 0, A1 = 0, A2 = 0, A3 = 0;
      for (int j = rs; j < re; ++j){
        union { _Float16 hh; unsigned short s; } uu; uu.s = AWs[j * 4 + h];
        float wv = (float)uu.hh;
        const unsigned short* hp = &HAs[srcL[j] * 264 + f4];
        A0 += wv * b2f(hp[0]); A1 += wv * b2f(hp[1]);
        A2 += wv * b2f(hp[2]); A3 += wv * b2f(hp[3]);
      }
      A0 += bz.x; A1 += bz.y; A2 += bz.z; A3 += bz.w;
      unsigned short o0 = f2b(A0 > 0.f ? A0 : 0.f);
      unsigned short o1 = f2b(A1 > 0.f ? A1 : 0.f);
      unsigned short o2 = f2b(A2 > 0.f ? A2 : 0.f);
      unsigned short o3 = f2b(A3 > 0.f ? A3 : 0.f);
      uint2 pk; pk.x = (unsigned int)o0 | ((unsigned int)o1 << 16);
      pk.y = (unsigned int)o2 | ((unsigned int)o3 << 16);
      *(uint2*)&HBs[n * 264 + f4] = pk;
    }
    __syncthreads();
  };

  //======== Layer 0 attention + agg: HA(h0) -> HB(P0) ========
  attn256(WOFF_G0AS, WOFF_G0AD);
  agg256(WOFF_G0B);

  //======== Layer 1 GEMM: h1 = P0(HB) @ g1W (K=256) -> HA ========
  #pragma unroll
  for (int i = 0; i < 16; ++i){ acc0[i] = (float4v){0,0,0,0}; acc1[i] = (float4v){0,0,0,0}; }
  for (int kc = 0; kc < 256; kc += 32){
    short8 a0 = *(const short8*)&HBs[(16 * w       + r) * 264 + kc + q * 8];
    short8 a1 = *(const short8*)&HBs[(16 * (w + 4) + r) * 264 + kc + q * 8];
    for (int nh = 0; nh < 2; ++nh){
      __syncthreads();
      #pragma unroll
      for (int p = 0; p < 2; ++p){
        int k2 = tid >> 3, c = (tid & 7) * 8;
        uint4 v = *(const uint4*)(BBF + BOFF_G1 + (size_t)(kc + k2) * 256 + nh * 128 + p * 64 + c);
        const unsigned short* vs = (const unsigned short*)&v;
        #pragma unroll
        for (int e = 0; e < 8; ++e) Bst[(p * 64 + c + e) * 40 + k2] = vs[e];
      }
      __syncthreads();
      #pragma unroll
      for (int nt = 0; nt < 8; ++nt){
        short8 bf = *(const short8*)&Bst[(16 * nt + r) * 40 + q * 8];
        acc0[nh * 8 + nt] = __builtin_amdgcn_mfma_f32_16x16x32_bf16(a0, bf, acc0[nh * 8 + nt], 0, 0, 0);
        acc1[nh * 8 + nt] = __builtin_amdgcn_mfma_f32_16x16x32_bf16(a1, bf, acc1[nh * 8 + nt], 0, 0, 0);
      }
    }
  }
  __syncthreads();
  #pragma unroll
  for (int nt = 0; nt < 16; ++nt)
    #pragma unroll
    for (int i = 0; i < 4; ++i){
      HAs[(16 * w       + q * 4 + i) * 264 + 16 * nt + r] = f2b(acc0[nt][i]);
      HAs[(16 * (w + 4) + q * 4 + i) * 264 + 16 * nt + r] = f2b(acc1[nt][i]);
    }
  __syncthreads();

  //======== Layer 1 attention + agg: HA(h1) -> HB(P1) ========
  attn256(WOFF_G1AS, WOFF_G1AD);
  agg256(WOFF_G1B);

  //======== Layer 2 GEMM: h2[128,64] = P1(HB) @ g2W (K=256) -> HA ========
  #pragma unroll
  for (int i = 0; i < 4; ++i){ acc0[i] = (float4v){0,0,0,0}; acc1[i] = (float4v){0,0,0,0}; }
  for (int kc = 0; kc < 256; kc += 32){
    short8 a0 = *(const short8*)&HBs[(16 * w       + r) * 264 + kc + q * 8];
    short8 a1 = *(const short8*)&HBs[(16 * (w + 4) + r) * 264 + kc + q * 8];
    __syncthreads();
    {
      int k2 = tid >> 3, c = (tid & 7) * 8;
      uint4 v = *(const uint4*)(BBF + BOFF_G2 + (size_t)(kc + k2) * 64 + c);
      const unsigned short* vs = (const unsigned short*)&v;
      #pragma unroll
      for (int e = 0; e < 8; ++e) Bst[(c + e) * 40 + k2] = vs[e];
    }
    __syncthreads();
    #pragma unroll
    for (int nt = 0; nt < 4; ++nt){
      short8 bf = *(const short8*)&Bst[(16 * nt + r) * 40 + q * 8];
      acc0[nt] = __builtin_amdgcn_mfma_f32_16x16x32_bf16(a0, bf, acc0[nt], 0, 0, 0);
      acc1[nt] = __builtin_amdgcn_mfma_f32_16x16x32_bf16(a1, bf, acc1[nt], 0, 0, 0);
    }
  }
  __syncthreads();
  #pragma unroll
  for (int nt = 0; nt < 4; ++nt)
    #pragma unroll
    for (int i = 0; i < 4; ++i){
      HAs[(16 * w       + q * 4 + i) * 264 + 16 * nt + r] = f2b(acc0[nt][i]);
      HAs[(16 * (w + 4) + q * 4 + i) * 264 + 16 * nt + r] = f2b(acc1[nt][i]);
    }
  __syncthreads();

  //======== Layer 2 attention (HD=64, 1 head) + agg + pool ========
  {
    float asv = Wbuf[WOFF_G2AS + lane];
    float adv = Wbuf[WOFF_G2AD + lane];
    for (int it = 0; it < 32; ++it){
      int n = it * 4 + w;
      float e0 = b2f(HAs[n * 264 + lane]);
      float vs = e0 * asv, vd = e0 * adv;
      #pragma unroll
      for (int m = 32; m >= 1; m >>= 1){ vs += __shfl_xor(vs, m); vd += __shfl_xor(vd, m); }
      if (lane == 0){ ALSs[n] = vs; ALDs[n] = vd; }
    }
    __syncthreads();
    if (tid < 128){
      int n = tid;
      float aldv = ALDs[n];
      int rs = rowL[n], re = rowL[n + 1];
      float mx = -3e38f, den = 0.f;
      for (int j = rs; j < re; ++j){
        float v = ALSs[srcL[j]] + aldv;
        v = v > 0.f ? v : 0.2f * v;
        if (v > mx){ den = den * __expf(mx - v) + 1.f; mx = v; }
        else den += __expf(v - mx);
      }
      float iden = 1.f / (den + 1e-16f);
      for (int j = rs; j < re; ++j){
        float v = ALSs[srcL[j]] + aldv;
        v = v > 0.f ? v : 0.2f * v;
        union { _Float16 hh; unsigned short s; } uu;
        uu.hh = (_Float16)(__expf(v - mx) * iden);
        AWs[j] = uu.s;
      }
    }
    __syncthreads();
    {
      int d = lane;
      float bz = Wbuf[WOFF_G2B + d];
      for (int n = w; n < 128; n += 4){
        int rs = rowL[n], re = rowL[n + 1];
        float A0 = 0.f;
        for (int j = rs; j < re; ++j){
          union { _Float16 hh; unsigned short s; } uu; uu.s = AWs[j];
          A0 += (float)uu.hh * b2f(HAs[srcL[j] * 264 + d]);
        }
        A0 += bz;
        HBs[n * 264 + d] = f2b(A0 > 0.f ? A0 : 0.f);
      }
    }
    __syncthreads();
    // pool: sum over 128 nodes
    {
      int f = lane, part = w;
      float s = 0.f;
      for (int n = part * 32; n < part * 32 + 32; ++n) s += b2f(HBs[n * 264 + f]);
      ALSs[part * 64 + f] = s;
    }
    __syncthreads();
    if (tid < 64){
      float s = ALSs[tid] + ALSs[64 + tid] + ALSs[128 + tid] + ALSs[192 + tid];
      int b = g >> 6, tq = g & 63;
      XSEQ[(size_t)(tq * BSZ + b) * HIDD + tid] = f2b(s);
    }
  }
}

// ---------------- MFMA matmul (kept for Wih): C = A(bf16) @ B(bf16) ----------------
template<int CBF16>
__global__ __launch_bounds__(256)
void mmx_kernel(const unsigned short* __restrict__ A, const unsigned short* __restrict__ Bb,
                void* __restrict__ Cv, int M, int Nc, int K)
{
  __shared__ unsigned short As[64][40];
  __shared__ unsigned short Bs[64][40];
  const int tid = threadIdx.x;
  const int w = tid >> 6, lane = tid & 63, q = lane >> 4, r = lane & 15;
  const int m0 = blockIdx.x * 64, n0 = blockIdx.y * 64;
  float4v acc0 = {0,0,0,0}, acc1 = {0,0,0,0}, acc2 = {0,0,0,0}, acc3 = {0,0,0,0};
  const int arow = tid >> 2, akb = (tid & 3) * 8;
  const int bk = tid >> 3, bnb = (tid & 7) * 8;
  for (int kc = 0; kc < K; kc += 32){
    int kw = K - kc; if (kw > 32) kw = 32;
    if (akb < kw){
      uint4 v = *(const uint4*)(A + (size_t)(m0 + arow) * K + kc + akb);
      *(uint4*)&As[arow][akb] = v;
    } else {
      uint4 z = {0,0,0,0}; *(uint4*)&As[arow][akb] = z;
    }
    if (bk < kw){
      uint4 v = *(const uint4*)(Bb + (size_t)(kc + bk) * Nc + n0 + bnb);
      const unsigned short* vs = (const unsigned short*)&v;
      #pragma unroll
      for (int e = 0; e < 8; ++e) Bs[bnb + e][bk] = vs[e];
    } else {
      #pragma unroll
      for (int e = 0; e < 8; ++e) Bs[bnb + e][bk] = 0;
    }
    __syncthreads();
    short8 af = *(const short8*)&As[16 * w + r][q * 8];
    short8 b0 = *(const short8*)&Bs[r][q * 8];
    short8 b1 = *(const short8*)&Bs[16 + r][q * 8];
    short8 b2 = *(const short8*)&Bs[32 + r][q * 8];
    short8 b3 = *(const short8*)&Bs[48 + r][q * 8];
    acc0 = __builtin_amdgcn_mfma_f32_16x16x32_bf16(af, b0, acc0, 0, 0, 0);
    acc1 = __builtin_amdgcn_mfma_f32_16x16x32_bf16(af, b1, acc1, 0, 0, 0);
    acc2 = __builtin_amdgcn_mfma_f32_16x16x32_bf16(af, b2, acc2, 0, 0, 0);
    acc3 = __builtin_amdgcn_mfma_f32_16x16x32_bf16(af, b3, acc3, 0, 0, 0);
    __syncthreads();
  }
  const int row = m0 + 16 * w + q * 4, col0 = n0 + r;
  if (CBF16){
    unsigned short* C = (unsigned short*)Cv;
    #pragma unroll
    for (int i = 0; i < 4; ++i){
      size_t base = (size_t)(row + i) * Nc;
      C[base + col0]      = f2b(acc0[i]);
      C[base + col0 + 16] = f2b(acc1[i]);
      C[base + col0 + 32] = f2b(acc2[i]);
      C[base + col0 + 48] = f2b(acc3[i]);
    }
  } else {
    float* C = (float*)Cv;
    #pragma unroll
    for (int i = 0; i < 4; ++i){
      size_t base = (size_t)(row + i) * Nc;
      C[base + col0]      = acc0[i];
      C[base + col0 + 16] = acc1[i];
      C[base + col0 + 32] = acc2[i];
      C[base + col0 + 48] = acc3[i];
    }
  }
}

// ---------------- pack Whh into f16-pair, interleaved: WT[d][kk4][u][c] ----------------
__global__ void packwhh_kernel(const float* __restrict__ Wbuf, unsigned int* __restrict__ WT){
  int id = blockIdx.x * blockDim.x + threadIdx.x;   // < 262144
  int d = id >> 17;
  int r = id & 131071;
  int c = r & 3;
  int u = (r >> 2) & 1023;
  int kk4 = r >> 12;
  int kk = kk4 * 4 + c;
  const float* W = Wbuf + (d ? WOFF_WHHB : WOFF_WHHF);
  _Float16 a = (_Float16)W[u * RHID + 2 * kk];
  _Float16 b = (_Float16)W[u * RHID + 2 * kk + 1];
  union { _Float16 h; unsigned short s; } ua, ub; ua.h = a; ub.h = b;
  WT[id] = (unsigned int)ua.s | ((unsigned int)ub.s << 16);
}

// ---------------- LSTM, M-split, shfl-pack publish + per-peer eager fetch ----------------
__global__ __launch_bounds__(256)
void lstm6_kernel(const float* __restrict__ XF, const float* __restrict__ XB,
                  const unsigned int* __restrict__ WT,
                  const float* __restrict__ bih_f, const float* __restrict__ bhh_f,
                  const float* __restrict__ bih_b, const float* __restrict__ bhh_b,
                  int* __restrict__ FLG, unsigned int* __restrict__ HX,
                  float* __restrict__ HT)
{
  __shared__ unsigned int WL[32][256][4];
  __shared__ unsigned int h2u[512];
  __shared__ float glds[4][64][5];

  const int tid = threadIdx.x;
  const int m = blockIdx.x & 3, dir = blockIdx.x >> 2;
  const int gq = tid >> 6, jl = tid & 63;
  const int u = gq * 256 + 64 * m + jl;
  const float* Xp = dir ? XB : XF;
  const float bias = (dir ? bih_b : bih_f)[u] + (dir ? bhh_b : bhh_f)[u];
  const int ub = tid >> 6, uj = tid & 63;
  int* FLGd = FLG + dir * 256;
  unsigned int* HXd = HX + dir * 1024;

  {
    const uint4* WT4 = (const uint4*)(WT + (dir << 17));
    #pragma unroll
    for (int kk4 = 0; kk4 < 32; ++kk4)
      *(uint4*)WL[kk4][tid] = WT4[(kk4 << 10) + u];
  }
  for (int i = tid; i < 512; i += 256) h2u[i] = 0;
  float c = 0.f;
  __syncthreads();

  for (int t = 0; t < TT; ++t){
    const int tb = dir ? (TT - 1 - t) : t;
    const float* xr = Xp + (size_t)(tb * 4) * 1024 + u;
    float a0 = bias + xr[0];
    float a1 = bias + xr[1024];
    float a2 = bias + xr[2048];
    float a3 = bias + xr[3072];
    #pragma unroll 4
    for (int kk4 = 0; kk4 < 32; ++kk4){
      uint4 w4 = *(const uint4*)WL[kk4][tid];
      uint4 hb0 = *(const uint4*)&h2u[0 * 128 + (kk4 << 2)];
      uint4 hb1 = *(const uint4*)&h2u[1 * 128 + (kk4 << 2)];
      uint4 hb2 = *(const uint4*)&h2u[2 * 128 + (kk4 << 2)];
      uint4 hb3 = *(const uint4*)&h2u[3 * 128 + (kk4 << 2)];
      a0 = dot2h(w4.x, hb0.x, a0); a0 = dot2h(w4.y, hb0.y, a0);
      a0 = dot2h(w4.z, hb0.z, a0); a0 = dot2h(w4.w, hb0.w, a0);
      a1 = dot2h(w4.x, hb1.x, a1); a1 = dot2h(w4.y, hb1.y, a1);
      a1 = dot2h(w4.z, hb1.z, a1); a1 = dot2h(w4.w, hb1.w, a1);
      a2 = dot2h(w4.x, hb2.x, a2); a2 = dot2h(w4.y, hb2.y, a2);
      a2 = dot2h(w4.z, hb2.z, a2); a2 = dot2h(w4.w, hb2.w, a2);
      a3 = dot2h(w4.x, hb3.x, a3); a3 = dot2h(w4.y, hb3.y, a3);
      a3 = dot2h(w4.z, hb3.z, a3); a3 = dot2h(w4.w, hb3.w, a3);
    }
    glds[gq][jl][0] = a0; glds[gq][jl][1] = a1;
    glds[gq][jl][2] = a2; glds[gq][jl][3] = a3;
    __syncthreads();

    float gi = glds[0][uj][ub];
    float gf = glds[1][uj][ub];
    float gg = glds[2][uj][ub];
    float go = glds[3][uj][ub];
    float si = 1.f / (1.f + __expf(-gi));
    float sf = 1.f / (1.f + __expf(-gf));
    float so = 1.f / (1.f + __expf(-go));
    float tg = 1.f - 2.f / (1.f + __expf(2.f * gg));
    c = sf * c + si * tg;
    float ch = 1.f - 2.f / (1.f + __expf(2.f * c));
    float hval = so * ch;
    if (t == TT - 1){
      HT[(size_t)(dir * 4 + ub) * RHID + (64 * m + uj)] = hval;
      break;
    }
    union { _Float16 h; unsigned short s; } uh; uh.h = (_Float16)hval;
    unsigned int own = uh.s;
    unsigned int partner = ((unsigned int)__shfl_xor((int)own, 1)) & 0xffffu;
    unsigned int* HXs = HXd + (t & 1) * 512;
    if ((uj & 1) == 0){
      unsigned int v = own | (partner << 16);
      int p = uj >> 1;
      h2u[ub * 128 + 32 * m + p] = v;
      __hip_atomic_store(&HXs[ub * 128 + 32 * m + p], v,
                         __ATOMIC_RELAXED, __HIP_MEMORY_SCOPE_AGENT);
    }
    __syncthreads();
    if (tid == 0)
      __hip_atomic_store(&FLGd[t * 4 + m], 1, __ATOMIC_RELEASE, __HIP_MEMORY_SCOPE_AGENT);
    if (gq > 0){
      int qp = (m + gq) & 3;
      if (jl == 0){
        int guard = 0;
        while (__hip_atomic_load(&FLGd[t * 4 + qp], __ATOMIC_ACQUIRE,
                                 __HIP_MEMORY_SCOPE_AGENT) == 0 && guard < 100000000){
          __builtin_amdgcn_s_sleep(1);
          ++guard;
        }
      }
      int b2 = jl >> 5, p2 = jl & 31;
      h2u[b2 * 128 + 32 * qp + p2] =
        __hip_atomic_load(&HXs[b2 * 128 + 32 * qp + p2],
                          __ATOMIC_RELAXED, __HIP_MEMORY_SCOPE_AGENT);
      h2u[(b2 + 2) * 128 + 32 * qp + p2] =
        __hip_atomic_load(&HXs[(b2 + 2) * 128 + 32 * qp + p2],
                          __ATOMIC_RELAXED, __HIP_MEMORY_SCOPE_AGENT);
    }
    __syncthreads();
  }
}

// ---------------- heads + Poincare projection, fp32 out ----------------
__global__ __launch_bounds__(512)
void head2_kernel(const float* __restrict__ HT,
                  const float* __restrict__ muW, const float* __restrict__ mub,
                  const float* __restrict__ lvW, const float* __restrict__ lvb,
                  float* __restrict__ out)
{
  __shared__ float feat[4][512];
  __shared__ float muv[4][64];
  __shared__ float lvv[4][64];
  int tid = threadIdx.x;
  for (int i = tid; i < 2048; i += 512){
    int rr = i >> 8, k = i & 255;
    int b = rr & 3, d = rr >> 2;
    feat[b][d * 256 + k] = HT[i];
  }
  __syncthreads();
  int w = tid >> 6, lane = tid & 63;
  for (int job = w; job < 512; job += 8){
    int j = job & 63, b = (job >> 6) & 3, mat = job >> 8;
    const float* W = (mat ? lvW : muW) + (size_t)j * 512;
    float s = 0.f;
    #pragma unroll
    for (int e = 0; e < 8; ++e) s += W[lane * 8 + e] * feat[b][lane * 8 + e];
    #pragma unroll
    for (int mm = 32; mm >= 1; mm >>= 1) s += __shfl_xor(s, mm);
    if (lane == 0){
      float v = s + (mat ? lvb[j] : mub[j]);
      if (mat) lvv[b][j] = v; else muv[b][j] = v;
    }
  }
  __syncthreads();
  if (tid < 256){
    int b = tid >> 6, j = tid & 63;
    float mu = muv[b][j];
    float sq = mu * mu;
    #pragma unroll
    for (int mm = 32; mm >= 1; mm >>= 1) sq += __shfl_xor(sq, mm);
    float nrm = sqrtf(sq);
    const float mxn = 1.0f - 4e-3f;
    if (nrm > mxn) mu = mu / nrm * mxn;
    out[b * 64 + j] = mu;
    out[256 + b * 64 + j] = lvv[b][j];
  }
}

extern "C" void kernel_launch(void* const* d_in, const int* in_sizes, int n_in,
                              void* d_out, int out_size, void* d_ws, size_t ws_size,
                              hipStream_t stream)
{
  const int* ei = (const int*)d_in[1];

  int*   ws_i    = (int*)d_ws;
  int*   dflag   = ws_i;
  int*   csr_row = ws_i + 256;
  int*   csr_src = ws_i + 512;
  int*   csr_dst = ws_i + 2048;
  float* FW   = (float*)d_ws;
  float* Wbuf = FW + FOFF_WBUF;
  float* XFp  = FW + FOFF_XFP;
  float* XBp  = FW + FOFF_XBP;
  float* HT   = FW + FOFF_HT;
  unsigned short* XSEQ = (unsigned short*)(FW + FOFF_XSEQ);
  unsigned short* Pb   = (unsigned short*)(FW + FOFF_P);
  unsigned int*   WT   = (unsigned int*)(FW + FOFF_WE);
  unsigned short* BBF  = (unsigned short*)(FW + FOFF_BBF);
  int*            FLG  = (int*)(FW + FOFF_SYNC);
  unsigned int*   HX   = (unsigned int*)(FW + FOFF_SYNC + 512);

  // ---- dtype sniff + canonicalize inputs ----
  sniff_kernel<<<1, 256, 0, stream>>>((const unsigned short*)d_in[2], dflag);

  CvtArgs ca;
  static const int wsz[24] = {4096,256,256,256, 65536,256,256,256, 16384,64,64,64,
                              65536,262144,1024,1024, 65536,262144,1024,1024,
                              32768,64,32768,64};
  {
    int acc = 0;
    for (int k = 0; k < 24; ++k){ ca.src[k] = d_in[2 + k]; ca.off[k] = acc; acc += wsz[k]; }
    ca.off[24] = acc;
  }
  cvtw_kernel<<<(WTOTAL + 255) / 256, 256, 0, stream>>>(ca, dflag, Wbuf);
  packb_kernel<<<(BTOTAL + 255) / 256, 256, 0, stream>>>(Wbuf, BBF);
  cvtx_kernel<<<(NTOT * NFEAT) / 256, 256, 0, stream>>>(d_in[0], dflag, Pb);
  csr_kernel<<<1, 256, 0, stream>>>(ei, csr_row, csr_src, csr_dst);

  // ---- fused GAT x3 + pool: one block per graph ----
  gatall_kernel<<<NGRAPH, 256, 0, stream>>>(Pb, BBF, Wbuf, csr_row, csr_src, XSEQ);

  // ---- LSTM input precompute ----
  mmx_kernel<0><<<dim3(4, 16), 256, 0, stream>>>(XSEQ, BBF + BOFF_WF, XFp, 256, 1024, 64);
  mmx_kernel<0><<<dim3(4, 16), 256, 0, stream>>>(XSEQ, BBF + BOFF_WB, XBp, 256, 1024, 64);

  // ---- pack + LSTM ----
  packwhh_kernel<<<1024, 256, 0, stream>>>(Wbuf, WT);
  hipMemsetAsync((void*)FLG, 0, 2048, stream);
  lstm6_kernel<<<8, 256, 0, stream>>>(XFp, XBp, WT,
                                      Wbuf + WOFF_BIHF, Wbuf + WOFF_BHHF,
                                      Wbuf + WOFF_BIHB, Wbuf + WOFF_BHHB,
                                      FLG, HX, HT);

  // ---- heads + projection ----
  head2_kernel<<<1, 512, 0, stream>>>(HT, Wbuf + WOFF_MUW, Wbuf + WOFF_MUB,
                                      Wbuf + WOFF_LVW, Wbuf + WOFF_LVB, (float*)d_out);
}